// Round 6
// baseline (733.338 us; speedup 1.0000x reference)
//
#include <hip/hip_runtime.h>
#include <hip/hip_bf16.h>

// ---------------------------------------------------------------------------
// Encoder: out = relu([features, mean_neigh(features)] @ W^T + b)
// N=100000, E=1e6 (undirected), D=64, H=128.
//
// Round 6: build_adj was still partial-line write bound (WRITE 104MB for 8MB
// payload): a node's ~20 adj writes spread over the full 2M-edge scan exceed
// L2 line residency. Fix = two-pass bucketed build:
//   pass A: bin (u,v) by u>>13 via LDS staging, flush 512B full-line chunks.
//   pass B: bucket b on XCD b%8 only; 1.3MB edges + 2MB adj slice fit one
//           L2 and writes are temporally dense -> lines drain once.
// Also: aggregate writes mean as bf16 in place (halves mean write+read).
//
// ws: cnt int[N] | gpos int[16] | adjmean int[N*64] (-> bf16 mean in place)
//     | gbuf ull[nbuk*bcap] (aliased by fb bf16[N*64] after pass B).
// ---------------------------------------------------------------------------

#define D_IN 64
#define H_OUT 128
#define CAP 64            // adjacency capacity; Poisson(20) => P(deg>64)~1e-14
#define NPB 32            // nodes per block in gemm kernel
#define BSHIFT 13         // 8192 nodes per bucket
#define NBUK_MAX 16
#define LCAP 160          // per-bucket LDS staging capacity (edges)

typedef unsigned long long ull;
typedef unsigned short ushortt;

__device__ __forceinline__ ushortt f2bf(float f) {
    __hip_bfloat16 h = __float2bfloat16(f);
    return *reinterpret_cast<ushortt*>(&h);
}
__device__ __forceinline__ float bf2f(ushortt u) {
    unsigned int x = ((unsigned int)u) << 16;
    return __uint_as_float(x);
}

// ---- pass A: bucket directed edges by u>>BSHIFT, coalesced 512B flushes ----
__global__ __launch_bounds__(256) void bucket_kernel(
    const int* __restrict__ ei,
    ull* __restrict__ gbuf,
    int* __restrict__ gpos,
    int E, int nbuk, int bcap)
{
    __shared__ ull lbuf[NBUK_MAX][LCAP];
    __shared__ int lcnt[NBUK_MAX];

    const int t    = threadIdx.x;
    const int lane = t & 63;
    const int wv   = t >> 6;
    const int E2   = 2 * E;

    if (t < nbuk) lcnt[t] = 0;
    __syncthreads();

    const int stride = gridDim.x * 256;
    for (int base = blockIdx.x * 256; base < E2; base += stride) {
        int i = base + t;
        if (i < E2) {
            int u = ei[i];
            int v = (i < E) ? ei[E + i] : ei[i - E];
            int b = u >> BSHIFT;
            ull pk = ((ull)(unsigned)v << 32) | (unsigned)u;
            int p = atomicAdd(&lcnt[b], 1);
            if (p < LCAP) {
                lbuf[b][p] = pk;
            } else {                       // statistically impossible overflow
                int gp = atomicAdd(&gpos[b], 1);
                if (gp < bcap) gbuf[(size_t)b * bcap + gp] = pk;
            }
        }
        __syncthreads();
        // flush full 64-edge chunks; one wave per bucket, no extra block syncs
        for (int b = wv; b < nbuk; b += 4) {
            int c = lcnt[b]; if (c > LCAP) c = LCAP;
            int f = (c >= 64) ? (c & ~63) : 0;
            if (f > 0) {
                int gbase = 0;
                if (lane == 0) gbase = atomicAdd(&gpos[b], f);
                gbase = __shfl(gbase, 0);
                for (int k = lane; k < f; k += 64) {
                    int gp = gbase + k;
                    if (gp < bcap) gbuf[(size_t)b * bcap + gp] = lbuf[b][k];
                }
                int rem = c - f;
                ull tmp = (lane < rem) ? lbuf[b][f + lane] : 0ull;
                if (lane < rem) lbuf[b][lane] = tmp;   // disjoint ranges
                if (lane == 0) lcnt[b] = rem;
            }
        }
        __syncthreads();
    }
    // final drain (<64 edges per bucket per block)
    for (int b = wv; b < nbuk; b += 4) {
        int c = lcnt[b]; if (c > LCAP) c = LCAP;
        if (c > 0) {
            int gbase = 0;
            if (lane == 0) gbase = atomicAdd(&gpos[b], c);
            gbase = __shfl(gbase, 0);
            for (int k = lane; k < c; k += 64) {
                int gp = gbase + k;
                if (gp < bcap) gbuf[(size_t)b * bcap + gp] = lbuf[b][k];
            }
        }
    }
}

// ---- pass B: build adjacency; bucket b pinned to XCD b%8 ----
__global__ __launch_bounds__(256) void adj_from_buckets_kernel(
    const ull* __restrict__ gbuf,
    const int* __restrict__ gpos,
    int* __restrict__ cnt,
    int* __restrict__ adj,
    int nbuk, int bcap)
{
    const int x   = blockIdx.x & 7;    // presumed XCD (round-robin dispatch)
    const int j   = blockIdx.x >> 3;   // block index within XCD group
    const int bpx = gridDim.x >> 3;    // blocks per XCD group

    for (int b = x; b < nbuk; b += 8) {
        int tot = gpos[b]; if (tot > bcap) tot = bcap;
        for (int i = j * 256 + (int)threadIdx.x; i < tot; i += bpx * 256) {
            ull pk = gbuf[(size_t)b * bcap + i];
            int u = (int)(unsigned)(pk & 0xffffffffu);
            int v = (int)(unsigned)(pk >> 32);
            int p = atomicAdd(&cnt[u], 1);
            if (p < CAP) adj[u * CAP + p] = v;
        }
    }
}

// ---- fallback build (round 5): XCD-partitioned single pass ----
__global__ __launch_bounds__(256) void build_adj_kernel(
    const int* __restrict__ ei,
    int* __restrict__ cnt,
    int* __restrict__ adj,
    int E)
{
    const int part   = blockIdx.x & 7;
    const int bloc   = blockIdx.x >> 3;
    const int nbp    = gridDim.x >> 3;
    const int stride = nbp * 256;
    const int E2     = 2 * E;

    for (int i = bloc * 256 + (int)threadIdx.x; i < E2; i += stride) {
        int u = ei[i];
        if (((u >> 4) & 7) != part) continue;
        int v = (i < E) ? ei[E + i] : ei[i - E];
        int p = atomicAdd(&cnt[u], 1);
        if (p < CAP) adj[u * CAP + p] = v;
    }
}

__global__ __launch_bounds__(256) void feat_to_bf16_kernel(
    const float4* __restrict__ f4,
    ushort4* __restrict__ out,
    int n4)
{
    int i = blockIdx.x * 256 + threadIdx.x;
    if (i >= n4) return;
    float4 v = f4[i];
    ushort4 o;
    o.x = f2bf(v.x); o.y = f2bf(v.y); o.z = f2bf(v.z); o.w = f2bf(v.w);
    out[i] = o;
}

// One wave per node, zero LDS. bf16 gather, fp32 accumulate; bf16 mean
// written in place over the adjacency row (row consumed first, in register).
__global__ __launch_bounds__(256) void aggregate_bf16_kernel(
    const ushortt* __restrict__ fb,
    int* __restrict__ adjmean,
    const int* __restrict__ cnt,
    int N)
{
    int wid  = (blockIdx.x * blockDim.x + threadIdx.x) >> 6;
    int lane = threadIdx.x & 63;
    if (wid >= N) return;

    int c  = cnt[wid];
    int cc = c < CAP ? c : CAP;
    int ids = adjmean[wid * CAP + lane];

    float sum = 0.0f;
    int j = 0;
    for (; j + 8 <= cc; j += 8) {
        int i0 = __shfl(ids, j + 0);
        int i1 = __shfl(ids, j + 1);
        int i2 = __shfl(ids, j + 2);
        int i3 = __shfl(ids, j + 3);
        int i4 = __shfl(ids, j + 4);
        int i5 = __shfl(ids, j + 5);
        int i6 = __shfl(ids, j + 6);
        int i7 = __shfl(ids, j + 7);
        float f0 = bf2f(fb[i0 * D_IN + lane]);
        float f1 = bf2f(fb[i1 * D_IN + lane]);
        float f2 = bf2f(fb[i2 * D_IN + lane]);
        float f3 = bf2f(fb[i3 * D_IN + lane]);
        float f4 = bf2f(fb[i4 * D_IN + lane]);
        float f5 = bf2f(fb[i5 * D_IN + lane]);
        float f6 = bf2f(fb[i6 * D_IN + lane]);
        float f7 = bf2f(fb[i7 * D_IN + lane]);
        sum += ((f0 + f1) + (f2 + f3)) + ((f4 + f5) + (f6 + f7));
    }
    for (; j < cc; ++j)
        sum += bf2f(fb[__shfl(ids, j) * D_IN + lane]);

    float m = sum / fmaxf((float)c, 1.0f);
    ushortt* mrow = (ushortt*)&adjmean[wid * CAP];
    mrow[lane] = f2bf(m);
}

// fp32-gather fallback (ws too small for fb); still emits bf16 mean.
__global__ __launch_bounds__(256) void aggregate_f32_kernel(
    const float* __restrict__ feat,
    int* __restrict__ adjmean,
    const int* __restrict__ cnt,
    int N)
{
    int wid  = (blockIdx.x * blockDim.x + threadIdx.x) >> 6;
    int lane = threadIdx.x & 63;
    if (wid >= N) return;

    int c  = cnt[wid];
    int cc = c < CAP ? c : CAP;
    int ids = adjmean[wid * CAP + lane];

    float sum = 0.0f;
    int j = 0;
    for (; j + 8 <= cc; j += 8) {
        int i0 = __shfl(ids, j + 0);
        int i1 = __shfl(ids, j + 1);
        int i2 = __shfl(ids, j + 2);
        int i3 = __shfl(ids, j + 3);
        int i4 = __shfl(ids, j + 4);
        int i5 = __shfl(ids, j + 5);
        int i6 = __shfl(ids, j + 6);
        int i7 = __shfl(ids, j + 7);
        float f0 = feat[i0 * D_IN + lane];
        float f1 = feat[i1 * D_IN + lane];
        float f2 = feat[i2 * D_IN + lane];
        float f3 = feat[i3 * D_IN + lane];
        float f4 = feat[i4 * D_IN + lane];
        float f5 = feat[i5 * D_IN + lane];
        float f6 = feat[i6 * D_IN + lane];
        float f7 = feat[i7 * D_IN + lane];
        sum += ((f0 + f1) + (f2 + f3)) + ((f4 + f5) + (f6 + f7));
    }
    for (; j < cc; ++j)
        sum += feat[__shfl(ids, j) * D_IN + lane];

    float m = sum / fmaxf((float)c, 1.0f);
    ushortt* mrow = (ushortt*)&adjmean[wid * CAP];
    mrow[lane] = f2bf(m);
}

// Tiled GEMM: out = relu([self(fp32) || mean(bf16)] @ W^T + b).
__global__ __launch_bounds__(256) void gemm_kernel(
    const int* __restrict__ nodes,
    const float* __restrict__ feat,
    const ushortt* __restrict__ meanb,   // row g at meanb + g*128, 64 used
    const float* __restrict__ W,
    const float* __restrict__ bias,
    float* __restrict__ out,
    int N)
{
    __shared__ float w_lds[64 * 132];
    __shared__ float comb_self[NPB * 68];
    __shared__ float comb_mean[NPB * 68];
    __shared__ int   gnode[NPB];

    const int t  = threadIdx.x;
    const int n0 = blockIdx.x * NPB;

    if (t < NPB) {
        int idx = n0 + t;
        if (idx >= N) idx = N - 1;
        gnode[t] = nodes[idx];
    }
    __syncthreads();

    for (int i = t; i < NPB * 64; i += 256) {
        int n = i >> 6, d = i & 63;
        int g = gnode[n];
        comb_self[n * 68 + d] = feat[g * D_IN + d];
        comb_mean[n * 68 + d] = bf2f(meanb[(size_t)g * 128 + d]);
    }
    for (int i = t; i < H_OUT * 64; i += 256) {
        int h = i >> 6, kk = i & 63;
        w_lds[kk * 132 + h] = W[h * (2 * D_IN) + kk];
    }
    __syncthreads();

    const int tx = t & 31;
    const int ty = t >> 5;
    const int h0 = tx * 4;
    const int nl = ty * 4;

    float acc[4][4];
#pragma unroll
    for (int j = 0; j < 4; j++)
#pragma unroll
        for (int i = 0; i < 4; i++) acc[j][i] = 0.0f;

    for (int kk = 0; kk < 64; kk += 4) {
        float4 wvv[4], cv[4];
#pragma unroll
        for (int i = 0; i < 4; i++)
            wvv[i] = *(const float4*)&w_lds[(kk + i) * 132 + h0];
#pragma unroll
        for (int j = 0; j < 4; j++)
            cv[j] = *(const float4*)&comb_self[(nl + j) * 68 + kk];
#pragma unroll
        for (int j = 0; j < 4; j++) {
            const float* c = (const float*)&cv[j];
#pragma unroll
            for (int i = 0; i < 4; i++) {
                const float* w = (const float*)&wvv[i];
                acc[j][0] += w[0] * c[i];
                acc[j][1] += w[1] * c[i];
                acc[j][2] += w[2] * c[i];
                acc[j][3] += w[3] * c[i];
            }
        }
    }
    __syncthreads();

    for (int i = t; i < H_OUT * 64; i += 256) {
        int h = i >> 6, kk = i & 63;
        w_lds[kk * 132 + h] = W[h * (2 * D_IN) + 64 + kk];
    }
    __syncthreads();

    for (int kk = 0; kk < 64; kk += 4) {
        float4 wvv[4], cv[4];
#pragma unroll
        for (int i = 0; i < 4; i++)
            wvv[i] = *(const float4*)&w_lds[(kk + i) * 132 + h0];
#pragma unroll
        for (int j = 0; j < 4; j++)
            cv[j] = *(const float4*)&comb_mean[(nl + j) * 68 + kk];
#pragma unroll
        for (int j = 0; j < 4; j++) {
            const float* c = (const float*)&cv[j];
#pragma unroll
            for (int i = 0; i < 4; i++) {
                const float* w = (const float*)&wvv[i];
                acc[j][0] += w[0] * c[i];
                acc[j][1] += w[1] * c[i];
                acc[j][2] += w[2] * c[i];
                acc[j][3] += w[3] * c[i];
            }
        }
    }

    float4 bv = *(const float4*)&bias[h0];
#pragma unroll
    for (int j = 0; j < 4; j++) {
        int n = n0 + nl + j;
        if (n >= N) continue;
        float4 o;
        o.x = fmaxf(acc[j][0] + bv.x, 0.0f);
        o.y = fmaxf(acc[j][1] + bv.y, 0.0f);
        o.z = fmaxf(acc[j][2] + bv.z, 0.0f);
        o.w = fmaxf(acc[j][3] + bv.w, 0.0f);
        *(float4*)&out[(size_t)n * H_OUT + h0] = o;
    }
}

extern "C" void kernel_launch(void* const* d_in, const int* in_sizes, int n_in,
                              void* d_out, int out_size, void* d_ws, size_t ws_size,
                              hipStream_t stream) {
    const int*   nodes = (const int*)d_in[0];
    const float* feat  = (const float*)d_in[1];
    const int*   ei    = (const int*)d_in[2];
    const float* W     = (const float*)d_in[3];
    const float* bias  = (const float*)d_in[4];
    float*       out   = (float*)d_out;

    const int N = in_sizes[0];
    const int E = in_sizes[2] / 2;

    int* cnt     = (int*)d_ws;
    int* gpos    = cnt + N;                       // 16 ints
    int* adjmean = gpos + 16;                     // int[N*CAP]
    ull* gbuf    = (ull*)(adjmean + (size_t)N * CAP);
    ushortt* fb  = (ushortt*)gbuf;                // aliases gbuf (safe: gbuf
                                                  // consumed before fb written)

    const int nbuk = (N + (1 << BSHIFT) - 1) >> BSHIFT;
    const int bcap = (int)(2.0 * E * (double)(1 << BSHIFT) / (double)N * 1.03)
                   + 8192;
    const size_t base_need   = (size_t)(N + 16) * 4 + (size_t)N * CAP * 4;
    const size_t need_bucket = base_need + (size_t)nbuk * bcap * 8;
    const size_t need_bf16   = base_need + (size_t)N * D_IN * 2;
    const bool use_bucket = (nbuk <= NBUK_MAX) && (ws_size >= need_bucket);
    const bool use_bf16   = (ws_size >= need_bf16);

    hipMemsetAsync(cnt, 0, (size_t)(N + 16) * sizeof(int), stream);

    if (use_bucket) {
        bucket_kernel<<<1024, 256, 0, stream>>>(ei, gbuf, gpos, E, nbuk, bcap);
        adj_from_buckets_kernel<<<512, 256, 0, stream>>>(gbuf, gpos, cnt,
                                                         adjmean, nbuk, bcap);
    } else {
        build_adj_kernel<<<2048, 256, 0, stream>>>(ei, cnt, adjmean, E);
    }

    int ablocks = ((size_t)N * 64 + 255) / 256;
    if (use_bf16) {
        int n4 = N * D_IN / 4;
        feat_to_bf16_kernel<<<(n4 + 255) / 256, 256, 0, stream>>>(
            (const float4*)feat, (ushort4*)fb, n4);
        aggregate_bf16_kernel<<<ablocks, 256, 0, stream>>>(fb, adjmean, cnt, N);
    } else {
        aggregate_f32_kernel<<<ablocks, 256, 0, stream>>>(feat, adjmean, cnt, N);
    }

    int gblocks = (N + NPB - 1) / NPB;
    gemm_kernel<<<gblocks, 256, 0, stream>>>(nodes, feat,
                                             (const ushortt*)adjmean,
                                             W, bias, out, N);
}

// Round 7
// 305.372 us; speedup vs baseline: 2.4015x; 2.4015x over previous
//
#include <hip/hip_runtime.h>
#include <hip/hip_bf16.h>

// ---------------------------------------------------------------------------
// Encoder: out = relu([features, mean_neigh(features)] @ W^T + b)
// N=100000, E=1e6 (undirected), D=64, H=128.
//
// Round 7: round-6's bucket pass A died (437us, VALUBusy 0.9%) on ONE bug:
// flush atomics on gpos[0..12] — a single 64B line hammered by 1024 blocks
// across 8 XCDs. Fix: per-block PRIVATE bucket segments indexed by per-block
// LDS counters -> zero global atomics in pass A. Entries are 4B:
// (v<<13)|(u&8191); the bucket id restores u's high bits. Pass B unchanged:
// bucket b pinned to XCD b%8; per-bucket working set (0.6MB entries + 2MB adj
// + 32KB cnt) < 4MB L2 so adj lines drain once.
//
// ws: cnt int[N] | ovfn int[16] | adjmean int[N*64] (-> bf16 mean in place)
//     | blkcnt int[256*16] | ovf ull[32768]
//     | big = max(gbuf uint[256*16*scap], fb bf16[N*64])  (gbuf consumed by
//       pass B before fb is written -> aliasing safe)
// Fallback chain (launch-constant): round-5 partitioned build / fp32 gather.
// ---------------------------------------------------------------------------

#define D_IN 64
#define H_OUT 128
#define CAP 64            // adjacency capacity; Poisson(20) => P(deg>64)~1e-14
#define NPB 32            // nodes per block in gemm kernel
#define BSHIFT 13         // 8192 nodes per bucket
#define NBUK_MAX 16
#define PASSA_BLOCKS 256
#define PASSA_THREADS 512
#define OVF_CAP 32768

typedef unsigned long long ull;
typedef unsigned short ushortt;

__device__ __forceinline__ ushortt f2bf(float f) {
    __hip_bfloat16 h = __float2bfloat16(f);
    return *reinterpret_cast<ushortt*>(&h);
}
__device__ __forceinline__ float bf2f(ushortt u) {
    unsigned int x = ((unsigned int)u) << 16;
    return __uint_as_float(x);
}

// ---- pass A: per-block private bucketing, no global atomics ----
__global__ __launch_bounds__(PASSA_THREADS) void bucket_a_kernel(
    const int* __restrict__ ei,
    unsigned* __restrict__ gbuf,
    int* __restrict__ blkcnt,
    ull* __restrict__ ovf,
    int* __restrict__ ovfn,
    int E, int scap, int chunk)
{
    __shared__ int lcnt[NBUK_MAX];
    const int t = threadIdx.x;
    if (t < NBUK_MAX) lcnt[t] = 0;
    __syncthreads();

    const int E2 = 2 * E;
    int lo = blockIdx.x * chunk;
    int hi = lo + chunk; if (hi > E2) hi = E2;

    for (int i = lo + t; i < hi; i += PASSA_THREADS) {
        int u = ei[i];
        int v = (i < E) ? ei[E + i] : ei[i - E];
        int b = u >> BSHIFT;
        unsigned pk = ((unsigned)v << BSHIFT) | (unsigned)(u & ((1 << BSHIFT) - 1));
        int p = atomicAdd(&lcnt[b], 1);          // LDS atomic: cheap
        if (p < scap) {
            gbuf[((size_t)blockIdx.x * NBUK_MAX + b) * scap + p] = pk;
        } else {                                  // statistically ~never
            int gp = atomicAdd(ovfn, 1);
            if (gp < OVF_CAP) ovf[gp] = ((ull)(unsigned)v << 32) | (unsigned)u;
        }
    }
    __syncthreads();
    if (t < NBUK_MAX) {
        int c = lcnt[t];
        blkcnt[blockIdx.x * NBUK_MAX + t] = c < scap ? c : scap;
    }
}

// ---- pass B: adjacency from buckets; bucket b pinned to XCD b%8 ----
__global__ __launch_bounds__(256) void adj_b_kernel(
    const unsigned* __restrict__ gbuf,
    const int* __restrict__ blkcnt,
    const ull* __restrict__ ovf,
    const int* __restrict__ ovfn,
    int* __restrict__ cnt,
    int* __restrict__ adj,
    int nbuk, int scap)
{
    const int x   = blockIdx.x & 7;    // presumed XCD (round-robin dispatch)
    const int j   = blockIdx.x >> 3;
    const int bpx = gridDim.x >> 3;

    for (int b = x; b < nbuk; b += 8) {
        for (int seg = j; seg < PASSA_BLOCKS; seg += bpx) {
            int c = blkcnt[seg * NBUK_MAX + b];
            const unsigned* base = gbuf + ((size_t)seg * NBUK_MAX + b) * scap;
            for (int i = threadIdx.x; i < c; i += 256) {
                unsigned e = base[i];
                int u = (b << BSHIFT) | (int)(e & ((1u << BSHIFT) - 1));
                int v = (int)(e >> BSHIFT);
                int p = atomicAdd(&cnt[u], 1);
                if (p < CAP) adj[u * CAP + p] = v;
            }
        }
    }
    if (blockIdx.x == 0) {             // overflow drain (expected empty)
        int n = *ovfn; if (n > OVF_CAP) n = OVF_CAP;
        for (int i = threadIdx.x; i < n; i += 256) {
            ull pk = ovf[i];
            int u = (int)(unsigned)(pk & 0xffffffffu);
            int v = (int)(unsigned)(pk >> 32);
            int p = atomicAdd(&cnt[u], 1);
            if (p < CAP) adj[u * CAP + p] = v;
        }
    }
}

// ---- fallback build (round 5): XCD-partitioned single pass ----
__global__ __launch_bounds__(256) void build_adj_kernel(
    const int* __restrict__ ei,
    int* __restrict__ cnt,
    int* __restrict__ adj,
    int E)
{
    const int part   = blockIdx.x & 7;
    const int bloc   = blockIdx.x >> 3;
    const int nbp    = gridDim.x >> 3;
    const int stride = nbp * 256;
    const int E2     = 2 * E;

    for (int i = bloc * 256 + (int)threadIdx.x; i < E2; i += stride) {
        int u = ei[i];
        if (((u >> 4) & 7) != part) continue;
        int v = (i < E) ? ei[E + i] : ei[i - E];
        int p = atomicAdd(&cnt[u], 1);
        if (p < CAP) adj[u * CAP + p] = v;
    }
}

__global__ __launch_bounds__(256) void feat_to_bf16_kernel(
    const float4* __restrict__ f4,
    ushort4* __restrict__ out,
    int n4)
{
    int i = blockIdx.x * 256 + threadIdx.x;
    if (i >= n4) return;
    float4 v = f4[i];
    ushort4 o;
    o.x = f2bf(v.x); o.y = f2bf(v.y); o.z = f2bf(v.z); o.w = f2bf(v.w);
    out[i] = o;
}

// One wave per node, zero LDS. bf16 gather, fp32 accumulate; bf16 mean
// written in place over the adjacency row (row consumed first, in register).
__global__ __launch_bounds__(256) void aggregate_bf16_kernel(
    const ushortt* __restrict__ fb,
    int* __restrict__ adjmean,
    const int* __restrict__ cnt,
    int N)
{
    int wid  = (blockIdx.x * blockDim.x + threadIdx.x) >> 6;
    int lane = threadIdx.x & 63;
    if (wid >= N) return;

    int c  = cnt[wid];
    int cc = c < CAP ? c : CAP;
    int ids = adjmean[wid * CAP + lane];

    float sum = 0.0f;
    int j = 0;
    for (; j + 8 <= cc; j += 8) {
        int i0 = __shfl(ids, j + 0);
        int i1 = __shfl(ids, j + 1);
        int i2 = __shfl(ids, j + 2);
        int i3 = __shfl(ids, j + 3);
        int i4 = __shfl(ids, j + 4);
        int i5 = __shfl(ids, j + 5);
        int i6 = __shfl(ids, j + 6);
        int i7 = __shfl(ids, j + 7);
        float f0 = bf2f(fb[i0 * D_IN + lane]);
        float f1 = bf2f(fb[i1 * D_IN + lane]);
        float f2 = bf2f(fb[i2 * D_IN + lane]);
        float f3 = bf2f(fb[i3 * D_IN + lane]);
        float f4 = bf2f(fb[i4 * D_IN + lane]);
        float f5 = bf2f(fb[i5 * D_IN + lane]);
        float f6 = bf2f(fb[i6 * D_IN + lane]);
        float f7 = bf2f(fb[i7 * D_IN + lane]);
        sum += ((f0 + f1) + (f2 + f3)) + ((f4 + f5) + (f6 + f7));
    }
    for (; j < cc; ++j)
        sum += bf2f(fb[__shfl(ids, j) * D_IN + lane]);

    float m = sum / fmaxf((float)c, 1.0f);
    ushortt* mrow = (ushortt*)&adjmean[wid * CAP];
    mrow[lane] = f2bf(m);
}

// fp32-gather fallback (ws too small for fb); still emits bf16 mean.
__global__ __launch_bounds__(256) void aggregate_f32_kernel(
    const float* __restrict__ feat,
    int* __restrict__ adjmean,
    const int* __restrict__ cnt,
    int N)
{
    int wid  = (blockIdx.x * blockDim.x + threadIdx.x) >> 6;
    int lane = threadIdx.x & 63;
    if (wid >= N) return;

    int c  = cnt[wid];
    int cc = c < CAP ? c : CAP;
    int ids = adjmean[wid * CAP + lane];

    float sum = 0.0f;
    int j = 0;
    for (; j + 8 <= cc; j += 8) {
        int i0 = __shfl(ids, j + 0);
        int i1 = __shfl(ids, j + 1);
        int i2 = __shfl(ids, j + 2);
        int i3 = __shfl(ids, j + 3);
        int i4 = __shfl(ids, j + 4);
        int i5 = __shfl(ids, j + 5);
        int i6 = __shfl(ids, j + 6);
        int i7 = __shfl(ids, j + 7);
        float f0 = feat[i0 * D_IN + lane];
        float f1 = feat[i1 * D_IN + lane];
        float f2 = feat[i2 * D_IN + lane];
        float f3 = feat[i3 * D_IN + lane];
        float f4 = feat[i4 * D_IN + lane];
        float f5 = feat[i5 * D_IN + lane];
        float f6 = feat[i6 * D_IN + lane];
        float f7 = feat[i7 * D_IN + lane];
        sum += ((f0 + f1) + (f2 + f3)) + ((f4 + f5) + (f6 + f7));
    }
    for (; j < cc; ++j)
        sum += feat[__shfl(ids, j) * D_IN + lane];

    float m = sum / fmaxf((float)c, 1.0f);
    ushortt* mrow = (ushortt*)&adjmean[wid * CAP];
    mrow[lane] = f2bf(m);
}

// Tiled GEMM: out = relu([self(fp32) || mean(bf16)] @ W^T + b).
__global__ __launch_bounds__(256) void gemm_kernel(
    const int* __restrict__ nodes,
    const float* __restrict__ feat,
    const ushortt* __restrict__ meanb,   // row g at meanb + g*128, 64 used
    const float* __restrict__ W,
    const float* __restrict__ bias,
    float* __restrict__ out,
    int N)
{
    __shared__ float w_lds[64 * 132];
    __shared__ float comb_self[NPB * 68];
    __shared__ float comb_mean[NPB * 68];
    __shared__ int   gnode[NPB];

    const int t  = threadIdx.x;
    const int n0 = blockIdx.x * NPB;

    if (t < NPB) {
        int idx = n0 + t;
        if (idx >= N) idx = N - 1;
        gnode[t] = nodes[idx];
    }
    __syncthreads();

    for (int i = t; i < NPB * 64; i += 256) {
        int n = i >> 6, d = i & 63;
        int g = gnode[n];
        comb_self[n * 68 + d] = feat[g * D_IN + d];
        comb_mean[n * 68 + d] = bf2f(meanb[(size_t)g * 128 + d]);
    }
    for (int i = t; i < H_OUT * 64; i += 256) {
        int h = i >> 6, kk = i & 63;
        w_lds[kk * 132 + h] = W[h * (2 * D_IN) + kk];
    }
    __syncthreads();

    const int tx = t & 31;
    const int ty = t >> 5;
    const int h0 = tx * 4;
    const int nl = ty * 4;

    float acc[4][4];
#pragma unroll
    for (int j = 0; j < 4; j++)
#pragma unroll
        for (int i = 0; i < 4; i++) acc[j][i] = 0.0f;

    for (int kk = 0; kk < 64; kk += 4) {
        float4 wvv[4], cv[4];
#pragma unroll
        for (int i = 0; i < 4; i++)
            wvv[i] = *(const float4*)&w_lds[(kk + i) * 132 + h0];
#pragma unroll
        for (int j = 0; j < 4; j++)
            cv[j] = *(const float4*)&comb_self[(nl + j) * 68 + kk];
#pragma unroll
        for (int j = 0; j < 4; j++) {
            const float* c = (const float*)&cv[j];
#pragma unroll
            for (int i = 0; i < 4; i++) {
                const float* w = (const float*)&wvv[i];
                acc[j][0] += w[0] * c[i];
                acc[j][1] += w[1] * c[i];
                acc[j][2] += w[2] * c[i];
                acc[j][3] += w[3] * c[i];
            }
        }
    }
    __syncthreads();

    for (int i = t; i < H_OUT * 64; i += 256) {
        int h = i >> 6, kk = i & 63;
        w_lds[kk * 132 + h] = W[h * (2 * D_IN) + 64 + kk];
    }
    __syncthreads();

    for (int kk = 0; kk < 64; kk += 4) {
        float4 wvv[4], cv[4];
#pragma unroll
        for (int i = 0; i < 4; i++)
            wvv[i] = *(const float4*)&w_lds[(kk + i) * 132 + h0];
#pragma unroll
        for (int j = 0; j < 4; j++)
            cv[j] = *(const float4*)&comb_mean[(nl + j) * 68 + kk];
#pragma unroll
        for (int j = 0; j < 4; j++) {
            const float* c = (const float*)&cv[j];
#pragma unroll
            for (int i = 0; i < 4; i++) {
                const float* w = (const float*)&wvv[i];
                acc[j][0] += w[0] * c[i];
                acc[j][1] += w[1] * c[i];
                acc[j][2] += w[2] * c[i];
                acc[j][3] += w[3] * c[i];
            }
        }
    }

    float4 bv = *(const float4*)&bias[h0];
#pragma unroll
    for (int j = 0; j < 4; j++) {
        int n = n0 + nl + j;
        if (n >= N) continue;
        float4 o;
        o.x = fmaxf(acc[j][0] + bv.x, 0.0f);
        o.y = fmaxf(acc[j][1] + bv.y, 0.0f);
        o.z = fmaxf(acc[j][2] + bv.z, 0.0f);
        o.w = fmaxf(acc[j][3] + bv.w, 0.0f);
        *(float4*)&out[(size_t)n * H_OUT + h0] = o;
    }
}

extern "C" void kernel_launch(void* const* d_in, const int* in_sizes, int n_in,
                              void* d_out, int out_size, void* d_ws, size_t ws_size,
                              hipStream_t stream) {
    const int*   nodes = (const int*)d_in[0];
    const float* feat  = (const float*)d_in[1];
    const int*   ei    = (const int*)d_in[2];
    const float* W     = (const float*)d_in[3];
    const float* bias  = (const float*)d_in[4];
    float*       out   = (float*)d_out;

    const int N = in_sizes[0];
    const int E = in_sizes[2] / 2;
    const int E2 = 2 * E;

    // ---- ws layout ----
    int*     cnt     = (int*)d_ws;                         // N ints
    int*     ovfn    = cnt + N;                            // 16 ints
    int*     adjmean = ovfn + 16;                          // N*CAP ints
    int*     blkcnt  = adjmean + (size_t)N * CAP;          // 256*16 ints
    ull*     ovf     = (ull*)(blkcnt + PASSA_BLOCKS * NBUK_MAX);
    unsigned* gbuf   = (unsigned*)(ovf + OVF_CAP);
    ushortt* fb      = (ushortt*)gbuf;                     // aliases gbuf

    const int nbuk  = (N + (1 << BSHIFT) - 1) >> BSHIFT;
    const int chunk = (E2 + PASSA_BLOCKS - 1) / PASSA_BLOCKS;
    // expected edges per block for the fullest bucket + 4 sigma, 16-aligned
    double ex = (double)chunk * (double)(1 << BSHIFT) / (double)N;
    int scap = ((int)(ex + 4.0 * __builtin_sqrt(ex)) + 31) & ~15;

    const size_t fixed = (size_t)N * 4 + 64 + (size_t)N * CAP * 4
                       + (size_t)PASSA_BLOCKS * NBUK_MAX * 4 + (size_t)OVF_CAP * 8;
    const size_t gbuf_b = (size_t)PASSA_BLOCKS * NBUK_MAX * scap * 4;
    const size_t fb_b   = (size_t)N * D_IN * 2;
    const size_t need_new  = fixed + (gbuf_b > fb_b ? gbuf_b : fb_b);
    const size_t need_bf16 = fixed + fb_b;

    const bool use_new  = (N <= (NBUK_MAX << BSHIFT)) && (ws_size >= need_new);
    const bool use_bf16 = (ws_size >= need_bf16);

    hipMemsetAsync(cnt, 0, ((size_t)N + 16) * sizeof(int), stream);

    if (use_new) {
        bucket_a_kernel<<<PASSA_BLOCKS, PASSA_THREADS, 0, stream>>>(
            ei, gbuf, blkcnt, ovf, ovfn, E, scap, chunk);
        adj_b_kernel<<<512, 256, 0, stream>>>(gbuf, blkcnt, ovf, ovfn,
                                              cnt, adjmean, nbuk, scap);
    } else {
        build_adj_kernel<<<2048, 256, 0, stream>>>(ei, cnt, adjmean, E);
    }

    int ablocks = ((size_t)N * 64 + 255) / 256;
    if (use_bf16) {
        int n4 = N * D_IN / 4;
        feat_to_bf16_kernel<<<(n4 + 255) / 256, 256, 0, stream>>>(
            (const float4*)feat, (ushort4*)fb, n4);
        aggregate_bf16_kernel<<<ablocks, 256, 0, stream>>>(fb, adjmean, cnt, N);
    } else {
        aggregate_f32_kernel<<<ablocks, 256, 0, stream>>>(feat, adjmean, cnt, N);
    }

    int gblocks = (N + NPB - 1) / NPB;
    gemm_kernel<<<gblocks, 256, 0, stream>>>(nodes, feat,
                                             (const ushortt*)adjmean,
                                             W, bias, out, N);
}

// Round 8
// 255.860 us; speedup vs baseline: 2.8662x; 1.1935x over previous
//
#include <hip/hip_runtime.h>
#include <hip/hip_bf16.h>

// ---------------------------------------------------------------------------
// Encoder: out = relu([features, mean_neigh(features)] @ W^T + b)
// N=100000, E=1e6 (undirected), D=64, H=128.
//
// Round 8: pass B was STILL partial-line write bound (WRITE 76.5MB / 8MB
// payload) -> L2 write-residency via blockIdx%8 pinning is not reliable.
// New pass B: one block per 256-node bucket assembles the bucket's whole
// adjacency in LDS (61 slots/node, stride 61 => 61*u mod 32 full bank
// permutation; true max degree ~45), then streams out ceil(cnt/4) uint4
// chunks per row. No scattered global 4B stores anywhere in the build.
// Pass A: per-block private segments (round 7, zero global atomics),
// 391 buckets, 4B entries (v<<8)|(u&255).
//
// ws: cnt int[N] | ovfn int[16] | adjmean int[N*64] (-> bf16 mean in place)
//     | blkcnt int[256*512] | ovf ull[32768]
//     | big = max(gbuf uint[256*nbuk*scap], fb bf16[N*64]) (gbuf consumed
//       by pass B before fb is written -> aliasing safe)
// ---------------------------------------------------------------------------

#define D_IN 64
#define H_OUT 128
#define CAP 64            // adjacency row stride (ints)
#define CAP_L 61          // LDS slots per node; max true degree ~45
#define NPB 32            // nodes per block in gemm kernel
#define BSHIFT 8          // 256 nodes per bucket
#define BUK_N 256
#define NBUK_MAX 512
#define PASSA_BLOCKS 256
#define PASSA_THREADS 512
#define OVF_CAP 32768

typedef unsigned long long ull;
typedef unsigned short ushortt;

__device__ __forceinline__ ushortt f2bf(float f) {
    __hip_bfloat16 h = __float2bfloat16(f);
    return *reinterpret_cast<ushortt*>(&h);
}
__device__ __forceinline__ float bf2f(ushortt u) {
    unsigned int x = ((unsigned int)u) << 16;
    return __uint_as_float(x);
}

// ---- pass A: per-block private bucketing, no global atomics ----
__global__ __launch_bounds__(PASSA_THREADS) void bucket_a_kernel(
    const int* __restrict__ ei,
    unsigned* __restrict__ gbuf,
    int* __restrict__ blkcnt,
    ull* __restrict__ ovf,
    int* __restrict__ ovfn,
    int E, int nbuk, int scap, int chunk)
{
    __shared__ int lcnt[NBUK_MAX];
    const int t = threadIdx.x;
    for (int i = t; i < nbuk; i += PASSA_THREADS) lcnt[i] = 0;
    __syncthreads();

    const int E2 = 2 * E;
    int lo = blockIdx.x * chunk;
    int hi = lo + chunk; if (hi > E2) hi = E2;

    for (int i = lo + t; i < hi; i += PASSA_THREADS) {
        int u = ei[i];
        int v = (i < E) ? ei[E + i] : ei[i - E];
        int b = u >> BSHIFT;
        unsigned pk = ((unsigned)v << BSHIFT) | (unsigned)(u & (BUK_N - 1));
        int p = atomicAdd(&lcnt[b], 1);          // LDS atomic: cheap
        if (p < scap) {
            gbuf[((size_t)blockIdx.x * nbuk + b) * scap + p] = pk;
        } else {                                  // statistically ~never
            int gp = atomicAdd(ovfn, 1);
            if (gp < OVF_CAP) ovf[gp] = ((ull)(unsigned)v << 32) | (unsigned)u;
        }
    }
    __syncthreads();
    for (int b = t; b < nbuk; b += PASSA_THREADS) {
        int c = lcnt[b];
        blkcnt[blockIdx.x * nbuk + b] = c < scap ? c : scap;
    }
}

// ---- pass B: one block per bucket; adjacency assembled in LDS ----
__global__ __launch_bounds__(512) void adj_lds_kernel(
    const unsigned* __restrict__ gbuf,
    const int* __restrict__ blkcnt,
    const ull* __restrict__ ovf,
    const int* __restrict__ ovfn,
    int* __restrict__ cnt,
    int* __restrict__ adj,
    int N, int nbuk, int scap)
{
    __shared__ unsigned adj_l[BUK_N * CAP_L];   // stride 61: bank-perm on node
    __shared__ int cnt_l[BUK_N];
    __shared__ int scnt_l[PASSA_BLOCKS];        // per-segment counts, staged

    const int b = blockIdx.x;
    const int t = threadIdx.x;

    if (t < BUK_N) cnt_l[t] = 0;
    if (t < PASSA_BLOCKS) scnt_l[t] = blkcnt[t * nbuk + b];
    __syncthreads();

    const int wv   = t >> 6;
    const int lane = t & 63;

    // scatter: wave wv handles segments wv, wv+8, ...
    for (int seg = wv; seg < PASSA_BLOCKS; seg += 8) {
        int c = scnt_l[seg];
        const unsigned* base = gbuf + ((size_t)seg * nbuk + b) * scap;
        for (int i = lane; i < c; i += 64) {
            unsigned e = base[i];
            int ul = e & (BUK_N - 1);
            int v  = (int)(e >> BSHIFT);
            int p  = atomicAdd(&cnt_l[ul], 1);
            if (p < CAP_L) adj_l[ul * CAP_L + p] = (unsigned)v;
        }
    }
    __syncthreads();

    // overflow entries for this bucket (expected none)
    int novf = *ovfn; if (novf > OVF_CAP) novf = OVF_CAP;
    for (int i = t; i < novf; i += 512) {
        ull pk = ovf[i];
        int u = (int)(unsigned)(pk & 0xffffffffu);
        if ((u >> BSHIFT) == b) {
            int v = (int)(unsigned)(pk >> 32);
            int ul = u & (BUK_N - 1);
            int p  = atomicAdd(&cnt_l[ul], 1);
            if (p < CAP_L) adj_l[ul * CAP_L + p] = (unsigned)v;
        }
    }
    __syncthreads();

    // write-out: thread t < 256 owns node row t; only ceil(c/4) uint4 chunks
    if (t < BUK_N) {
        int g = (b << BSHIFT) + t;
        if (g < N) {
            int c = cnt_l[t];
            cnt[g] = c;
            int cl = c < CAP_L ? c : CAP_L;
            int k4 = (cl + 3) >> 2;
            for (int s = 0; s < k4; ++s) {
                uint4 o;
                o.x = adj_l[t * CAP_L + 4 * s + 0];
                o.y = adj_l[t * CAP_L + 4 * s + 1];
                o.z = adj_l[t * CAP_L + 4 * s + 2];
                o.w = adj_l[t * CAP_L + 4 * s + 3];
                *(uint4*)&adj[(size_t)g * CAP + 4 * s] = o;
            }
        }
    }
}

// ---- fallback build (round 5): XCD-partitioned single pass ----
__global__ __launch_bounds__(256) void build_adj_kernel(
    const int* __restrict__ ei,
    int* __restrict__ cnt,
    int* __restrict__ adj,
    int E)
{
    const int part   = blockIdx.x & 7;
    const int bloc   = blockIdx.x >> 3;
    const int nbp    = gridDim.x >> 3;
    const int stride = nbp * 256;
    const int E2     = 2 * E;

    for (int i = bloc * 256 + (int)threadIdx.x; i < E2; i += stride) {
        int u = ei[i];
        if (((u >> 4) & 7) != part) continue;
        int v = (i < E) ? ei[E + i] : ei[i - E];
        int p = atomicAdd(&cnt[u], 1);
        if (p < CAP_L) adj[u * CAP + p] = v;
    }
}

__global__ __launch_bounds__(256) void feat_to_bf16_kernel(
    const float4* __restrict__ f4,
    ushort4* __restrict__ out,
    int n4)
{
    int i = blockIdx.x * 256 + threadIdx.x;
    if (i >= n4) return;
    float4 v = f4[i];
    ushort4 o;
    o.x = f2bf(v.x); o.y = f2bf(v.y); o.z = f2bf(v.z); o.w = f2bf(v.w);
    out[i] = o;
}

// One wave per node, zero LDS. bf16 gather, fp32 accumulate; bf16 mean
// written in place over the adjacency row (row consumed first, in register).
__global__ __launch_bounds__(256) void aggregate_bf16_kernel(
    const ushortt* __restrict__ fb,
    int* __restrict__ adjmean,
    const int* __restrict__ cnt,
    int N)
{
    int wid  = (blockIdx.x * blockDim.x + threadIdx.x) >> 6;
    int lane = threadIdx.x & 63;
    if (wid >= N) return;

    int c  = cnt[wid];
    int cc = c < CAP_L ? c : CAP_L;
    int ids = adjmean[wid * CAP + lane];

    float sum = 0.0f;
    int j = 0;
    for (; j + 8 <= cc; j += 8) {
        int i0 = __shfl(ids, j + 0);
        int i1 = __shfl(ids, j + 1);
        int i2 = __shfl(ids, j + 2);
        int i3 = __shfl(ids, j + 3);
        int i4 = __shfl(ids, j + 4);
        int i5 = __shfl(ids, j + 5);
        int i6 = __shfl(ids, j + 6);
        int i7 = __shfl(ids, j + 7);
        float f0 = bf2f(fb[i0 * D_IN + lane]);
        float f1 = bf2f(fb[i1 * D_IN + lane]);
        float f2 = bf2f(fb[i2 * D_IN + lane]);
        float f3 = bf2f(fb[i3 * D_IN + lane]);
        float f4 = bf2f(fb[i4 * D_IN + lane]);
        float f5 = bf2f(fb[i5 * D_IN + lane]);
        float f6 = bf2f(fb[i6 * D_IN + lane]);
        float f7 = bf2f(fb[i7 * D_IN + lane]);
        sum += ((f0 + f1) + (f2 + f3)) + ((f4 + f5) + (f6 + f7));
    }
    for (; j < cc; ++j)
        sum += bf2f(fb[__shfl(ids, j) * D_IN + lane]);

    float m = sum / fmaxf((float)c, 1.0f);
    ushortt* mrow = (ushortt*)&adjmean[wid * CAP];
    mrow[lane] = f2bf(m);
}

// fp32-gather fallback (ws too small for fb); still emits bf16 mean.
__global__ __launch_bounds__(256) void aggregate_f32_kernel(
    const float* __restrict__ feat,
    int* __restrict__ adjmean,
    const int* __restrict__ cnt,
    int N)
{
    int wid  = (blockIdx.x * blockDim.x + threadIdx.x) >> 6;
    int lane = threadIdx.x & 63;
    if (wid >= N) return;

    int c  = cnt[wid];
    int cc = c < CAP_L ? c : CAP_L;
    int ids = adjmean[wid * CAP + lane];

    float sum = 0.0f;
    int j = 0;
    for (; j + 8 <= cc; j += 8) {
        int i0 = __shfl(ids, j + 0);
        int i1 = __shfl(ids, j + 1);
        int i2 = __shfl(ids, j + 2);
        int i3 = __shfl(ids, j + 3);
        int i4 = __shfl(ids, j + 4);
        int i5 = __shfl(ids, j + 5);
        int i6 = __shfl(ids, j + 6);
        int i7 = __shfl(ids, j + 7);
        float f0 = feat[i0 * D_IN + lane];
        float f1 = feat[i1 * D_IN + lane];
        float f2 = feat[i2 * D_IN + lane];
        float f3 = feat[i3 * D_IN + lane];
        float f4 = feat[i4 * D_IN + lane];
        float f5 = feat[i5 * D_IN + lane];
        float f6 = feat[i6 * D_IN + lane];
        float f7 = feat[i7 * D_IN + lane];
        sum += ((f0 + f1) + (f2 + f3)) + ((f4 + f5) + (f6 + f7));
    }
    for (; j < cc; ++j)
        sum += feat[__shfl(ids, j) * D_IN + lane];

    float m = sum / fmaxf((float)c, 1.0f);
    ushortt* mrow = (ushortt*)&adjmean[wid * CAP];
    mrow[lane] = f2bf(m);
}

// Tiled GEMM: out = relu([self(fp32) || mean(bf16)] @ W^T + b).
__global__ __launch_bounds__(256) void gemm_kernel(
    const int* __restrict__ nodes,
    const float* __restrict__ feat,
    const ushortt* __restrict__ meanb,   // row g at meanb + g*128, 64 used
    const float* __restrict__ W,
    const float* __restrict__ bias,
    float* __restrict__ out,
    int N)
{
    __shared__ float w_lds[64 * 132];
    __shared__ float comb_self[NPB * 68];
    __shared__ float comb_mean[NPB * 68];
    __shared__ int   gnode[NPB];

    const int t  = threadIdx.x;
    const int n0 = blockIdx.x * NPB;

    if (t < NPB) {
        int idx = n0 + t;
        if (idx >= N) idx = N - 1;
        gnode[t] = nodes[idx];
    }
    __syncthreads();

    for (int i = t; i < NPB * 64; i += 256) {
        int n = i >> 6, d = i & 63;
        int g = gnode[n];
        comb_self[n * 68 + d] = feat[g * D_IN + d];
        comb_mean[n * 68 + d] = bf2f(meanb[(size_t)g * 128 + d]);
    }
    for (int i = t; i < H_OUT * 64; i += 256) {
        int h = i >> 6, kk = i & 63;
        w_lds[kk * 132 + h] = W[h * (2 * D_IN) + kk];
    }
    __syncthreads();

    const int tx = t & 31;
    const int ty = t >> 5;
    const int h0 = tx * 4;
    const int nl = ty * 4;

    float acc[4][4];
#pragma unroll
    for (int j = 0; j < 4; j++)
#pragma unroll
        for (int i = 0; i < 4; i++) acc[j][i] = 0.0f;

    for (int kk = 0; kk < 64; kk += 4) {
        float4 wvv[4], cv[4];
#pragma unroll
        for (int i = 0; i < 4; i++)
            wvv[i] = *(const float4*)&w_lds[(kk + i) * 132 + h0];
#pragma unroll
        for (int j = 0; j < 4; j++)
            cv[j] = *(const float4*)&comb_self[(nl + j) * 68 + kk];
#pragma unroll
        for (int j = 0; j < 4; j++) {
            const float* c = (const float*)&cv[j];
#pragma unroll
            for (int i = 0; i < 4; i++) {
                const float* w = (const float*)&wvv[i];
                acc[j][0] += w[0] * c[i];
                acc[j][1] += w[1] * c[i];
                acc[j][2] += w[2] * c[i];
                acc[j][3] += w[3] * c[i];
            }
        }
    }
    __syncthreads();

    for (int i = t; i < H_OUT * 64; i += 256) {
        int h = i >> 6, kk = i & 63;
        w_lds[kk * 132 + h] = W[h * (2 * D_IN) + 64 + kk];
    }
    __syncthreads();

    for (int kk = 0; kk < 64; kk += 4) {
        float4 wvv[4], cv[4];
#pragma unroll
        for (int i = 0; i < 4; i++)
            wvv[i] = *(const float4*)&w_lds[(kk + i) * 132 + h0];
#pragma unroll
        for (int j = 0; j < 4; j++)
            cv[j] = *(const float4*)&comb_mean[(nl + j) * 68 + kk];
#pragma unroll
        for (int j = 0; j < 4; j++) {
            const float* c = (const float*)&cv[j];
#pragma unroll
            for (int i = 0; i < 4; i++) {
                const float* w = (const float*)&wvv[i];
                acc[j][0] += w[0] * c[i];
                acc[j][1] += w[1] * c[i];
                acc[j][2] += w[2] * c[i];
                acc[j][3] += w[3] * c[i];
            }
        }
    }

    float4 bv = *(const float4*)&bias[h0];
#pragma unroll
    for (int j = 0; j < 4; j++) {
        int n = n0 + nl + j;
        if (n >= N) continue;
        float4 o;
        o.x = fmaxf(acc[j][0] + bv.x, 0.0f);
        o.y = fmaxf(acc[j][1] + bv.y, 0.0f);
        o.z = fmaxf(acc[j][2] + bv.z, 0.0f);
        o.w = fmaxf(acc[j][3] + bv.w, 0.0f);
        *(float4*)&out[(size_t)n * H_OUT + h0] = o;
    }
}

extern "C" void kernel_launch(void* const* d_in, const int* in_sizes, int n_in,
                              void* d_out, int out_size, void* d_ws, size_t ws_size,
                              hipStream_t stream) {
    const int*   nodes = (const int*)d_in[0];
    const float* feat  = (const float*)d_in[1];
    const int*   ei    = (const int*)d_in[2];
    const float* W     = (const float*)d_in[3];
    const float* bias  = (const float*)d_in[4];
    float*       out   = (float*)d_out;

    const int N  = in_sizes[0];
    const int E  = in_sizes[2] / 2;
    const int E2 = 2 * E;

    const int nbuk  = (N + BUK_N - 1) >> BSHIFT;
    const int chunk = (E2 + PASSA_BLOCKS - 1) / PASSA_BLOCKS;
    // expected entries per (block,bucket) + 5 sigma, 16-aligned
    double ex = (double)chunk * (double)BUK_N / (double)N;
    int scap = ((int)(ex + 5.0 * __builtin_sqrt(ex)) + 31) & ~15;

    // ---- ws layout ----
    int*      cnt     = (int*)d_ws;                        // N ints
    int*      ovfn    = cnt + N;                           // 16 ints
    int*      adjmean = ovfn + 16;                         // N*CAP ints
    int*      blkcnt  = adjmean + (size_t)N * CAP;         // 256*nbuk ints
    ull*      ovf     = (ull*)(blkcnt + (size_t)PASSA_BLOCKS * NBUK_MAX);
    unsigned* gbuf    = (unsigned*)(ovf + OVF_CAP);
    ushortt*  fb      = (ushortt*)gbuf;                    // aliases gbuf

    const size_t fixed = (size_t)N * 4 + 64 + (size_t)N * CAP * 4
                       + (size_t)PASSA_BLOCKS * NBUK_MAX * 4
                       + (size_t)OVF_CAP * 8;
    const size_t gbuf_b = (size_t)PASSA_BLOCKS * nbuk * scap * 4;
    const size_t fb_b   = (size_t)N * D_IN * 2;
    const size_t need_new  = fixed + (gbuf_b > fb_b ? gbuf_b : fb_b);
    const size_t need_bf16 = fixed + fb_b;

    const bool use_new  = (N <= 131072) && (nbuk <= NBUK_MAX)
                        && (ws_size >= need_new);
    const bool use_bf16 = (ws_size >= need_bf16);

    if (use_new) {
        hipMemsetAsync(ovfn, 0, 16 * sizeof(int), stream);  // cnt written by B
        bucket_a_kernel<<<PASSA_BLOCKS, PASSA_THREADS, 0, stream>>>(
            ei, gbuf, blkcnt, ovf, ovfn, E, nbuk, scap, chunk);
        adj_lds_kernel<<<nbuk, 512, 0, stream>>>(gbuf, blkcnt, ovf, ovfn,
                                                 cnt, adjmean, N, nbuk, scap);
    } else {
        hipMemsetAsync(cnt, 0, ((size_t)N + 16) * sizeof(int), stream);
        build_adj_kernel<<<2048, 256, 0, stream>>>(ei, cnt, adjmean, E);
    }

    int ablocks = ((size_t)N * 64 + 255) / 256;
    if (use_bf16) {
        int n4 = N * D_IN / 4;
        feat_to_bf16_kernel<<<(n4 + 255) / 256, 256, 0, stream>>>(
            (const float4*)feat, (ushort4*)fb, n4);
        aggregate_bf16_kernel<<<ablocks, 256, 0, stream>>>(fb, adjmean, cnt, N);
    } else {
        aggregate_f32_kernel<<<ablocks, 256, 0, stream>>>(feat, adjmean, cnt, N);
    }

    int gblocks = (N + NPB - 1) / NPB;
    gemm_kernel<<<gblocks, 256, 0, stream>>>(nodes, feat,
                                             (const ushortt*)adjmean,
                                             W, bias, out, N);
}

// Round 9
// 217.461 us; speedup vs baseline: 3.3723x; 1.1766x over previous
//
#include <hip/hip_runtime.h>
#include <hip/hip_bf16.h>

// ---------------------------------------------------------------------------
// Encoder: out = relu([features, mean_neigh(features)] @ W^T + b)
// N=100000, E=1e6 (undirected), D=64, H=128.
//
// Round 9: replace the scalar-FMA gemm (72us, VALUBusy 52%, 29% of fp32
// vector peak, occupancy-capped) with a bf16 MFMA gemm (16x16x32):
//   - self half = fb (bf16 features, already staged for the gather)
//   - mean half = fm (compact bf16 means, new aggregate output)
//   - W converted once to bf16 (32KB), staged in LDS stride 136 shorts
//     (68 dwords = 4 mod 32 -> only free 2-way b128 aliasing)
//   - A-frags 16B/lane from global; 8 col-tiles x 4 mfma per wave;
//     C/D: col=lane&15, row=quad*4+reg; 64B-sector stores.
// Build pipeline unchanged from round 8 (LDS-assembled adjacency).
//
// ws: cnt | ovfn | adjmean | blkcnt | ovf | Wb | big{gbuf -> fb|fm}
// (gbuf consumed by pass B before fb/fm are written -> aliasing safe)
// ---------------------------------------------------------------------------

#define D_IN 64
#define H_OUT 128
#define CAP 64            // adjacency row stride (ints)
#define CAP_L 61          // LDS slots per node; max true degree ~45
#define NPB 32            // nodes per block in fallback gemm
#define BSHIFT 8          // 256 nodes per bucket
#define BUK_N 256
#define NBUK_MAX 512
#define PASSA_BLOCKS 256
#define PASSA_THREADS 512
#define OVF_CAP 32768

typedef unsigned long long ull;
typedef unsigned short ushortt;
typedef __attribute__((ext_vector_type(8))) short bf16x8;
typedef __attribute__((ext_vector_type(4))) float f32x4;

__device__ __forceinline__ ushortt f2bf(float f) {
    __hip_bfloat16 h = __float2bfloat16(f);
    return *reinterpret_cast<ushortt*>(&h);
}
__device__ __forceinline__ float bf2f(ushortt u) {
    unsigned int x = ((unsigned int)u) << 16;
    return __uint_as_float(x);
}

// ---- pass A: per-block private bucketing, no global atomics ----
__global__ __launch_bounds__(PASSA_THREADS) void bucket_a_kernel(
    const int* __restrict__ ei,
    unsigned* __restrict__ gbuf,
    int* __restrict__ blkcnt,
    ull* __restrict__ ovf,
    int* __restrict__ ovfn,
    int E, int nbuk, int scap, int chunk)
{
    __shared__ int lcnt[NBUK_MAX];
    const int t = threadIdx.x;
    for (int i = t; i < nbuk; i += PASSA_THREADS) lcnt[i] = 0;
    __syncthreads();

    const int E2 = 2 * E;
    int lo = blockIdx.x * chunk;
    int hi = lo + chunk; if (hi > E2) hi = E2;

    for (int i = lo + t; i < hi; i += PASSA_THREADS) {
        int u = ei[i];
        int v = (i < E) ? ei[E + i] : ei[i - E];
        int b = u >> BSHIFT;
        unsigned pk = ((unsigned)v << BSHIFT) | (unsigned)(u & (BUK_N - 1));
        int p = atomicAdd(&lcnt[b], 1);          // LDS atomic: cheap
        if (p < scap) {
            gbuf[((size_t)blockIdx.x * nbuk + b) * scap + p] = pk;
        } else {                                  // statistically ~never
            int gp = atomicAdd(ovfn, 1);
            if (gp < OVF_CAP) ovf[gp] = ((ull)(unsigned)v << 32) | (unsigned)u;
        }
    }
    __syncthreads();
    for (int b = t; b < nbuk; b += PASSA_THREADS) {
        int c = lcnt[b];
        blkcnt[blockIdx.x * nbuk + b] = c < scap ? c : scap;
    }
}

// ---- pass B: one block per bucket; adjacency assembled in LDS ----
__global__ __launch_bounds__(512) void adj_lds_kernel(
    const unsigned* __restrict__ gbuf,
    const int* __restrict__ blkcnt,
    const ull* __restrict__ ovf,
    const int* __restrict__ ovfn,
    int* __restrict__ cnt,
    int* __restrict__ adj,
    int N, int nbuk, int scap)
{
    __shared__ unsigned adj_l[BUK_N * CAP_L];   // stride 61: bank-perm on node
    __shared__ int cnt_l[BUK_N];
    __shared__ int scnt_l[PASSA_BLOCKS];

    const int b = blockIdx.x;
    const int t = threadIdx.x;

    if (t < BUK_N) cnt_l[t] = 0;
    if (t < PASSA_BLOCKS) scnt_l[t] = blkcnt[t * nbuk + b];
    __syncthreads();

    const int wv   = t >> 6;
    const int lane = t & 63;

    for (int seg = wv; seg < PASSA_BLOCKS; seg += 8) {
        int c = scnt_l[seg];
        const unsigned* base = gbuf + ((size_t)seg * nbuk + b) * scap;
        for (int i = lane; i < c; i += 64) {
            unsigned e = base[i];
            int ul = e & (BUK_N - 1);
            int v  = (int)(e >> BSHIFT);
            int p  = atomicAdd(&cnt_l[ul], 1);
            if (p < CAP_L) adj_l[ul * CAP_L + p] = (unsigned)v;
        }
    }
    __syncthreads();

    int novf = *ovfn; if (novf > OVF_CAP) novf = OVF_CAP;
    for (int i = t; i < novf; i += 512) {
        ull pk = ovf[i];
        int u = (int)(unsigned)(pk & 0xffffffffu);
        if ((u >> BSHIFT) == b) {
            int v = (int)(unsigned)(pk >> 32);
            int ul = u & (BUK_N - 1);
            int p  = atomicAdd(&cnt_l[ul], 1);
            if (p < CAP_L) adj_l[ul * CAP_L + p] = (unsigned)v;
        }
    }
    __syncthreads();

    if (t < BUK_N) {
        int g = (b << BSHIFT) + t;
        if (g < N) {
            int c = cnt_l[t];
            cnt[g] = c;
            int cl = c < CAP_L ? c : CAP_L;
            int k4 = (cl + 3) >> 2;
            for (int s = 0; s < k4; ++s) {
                uint4 o;
                o.x = adj_l[t * CAP_L + 4 * s + 0];
                o.y = adj_l[t * CAP_L + 4 * s + 1];
                o.z = adj_l[t * CAP_L + 4 * s + 2];
                o.w = adj_l[t * CAP_L + 4 * s + 3];
                *(uint4*)&adj[(size_t)g * CAP + 4 * s] = o;
            }
        }
    }
}

// ---- fallback build (round 5): XCD-partitioned single pass ----
__global__ __launch_bounds__(256) void build_adj_kernel(
    const int* __restrict__ ei,
    int* __restrict__ cnt,
    int* __restrict__ adj,
    int E)
{
    const int part   = blockIdx.x & 7;
    const int bloc   = blockIdx.x >> 3;
    const int nbp    = gridDim.x >> 3;
    const int stride = nbp * 256;
    const int E2     = 2 * E;

    for (int i = bloc * 256 + (int)threadIdx.x; i < E2; i += stride) {
        int u = ei[i];
        if (((u >> 4) & 7) != part) continue;
        int v = (i < E) ? ei[E + i] : ei[i - E];
        int p = atomicAdd(&cnt[u], 1);
        if (p < CAP_L) adj[u * CAP + p] = v;
    }
}

__global__ __launch_bounds__(256) void feat_to_bf16_kernel(
    const float4* __restrict__ f4,
    ushort4* __restrict__ out,
    int n4)
{
    int i = blockIdx.x * 256 + threadIdx.x;
    if (i >= n4) return;
    float4 v = f4[i];
    ushort4 o;
    o.x = f2bf(v.x); o.y = f2bf(v.y); o.z = f2bf(v.z); o.w = f2bf(v.w);
    out[i] = o;
}

// W [128][128] fp32 -> bf16, same layout
__global__ __launch_bounds__(256) void w_to_bf16_kernel(
    const float4* __restrict__ w4,
    ushort4* __restrict__ out,
    int n4)
{
    int i = blockIdx.x * 256 + threadIdx.x;
    if (i >= n4) return;
    float4 v = w4[i];
    ushort4 o;
    o.x = f2bf(v.x); o.y = f2bf(v.y); o.z = f2bf(v.z); o.w = f2bf(v.w);
    out[i] = o;
}

// One wave per node. bf16 gather, fp32 accumulate; COMPACT bf16 mean out.
__global__ __launch_bounds__(256) void aggregate_compact_kernel(
    const ushortt* __restrict__ fb,
    const int* __restrict__ adj,
    const int* __restrict__ cnt,
    ushortt* __restrict__ fm,
    int N)
{
    int wid  = (blockIdx.x * blockDim.x + threadIdx.x) >> 6;
    int lane = threadIdx.x & 63;
    if (wid >= N) return;

    int c  = cnt[wid];
    int cc = c < CAP_L ? c : CAP_L;
    int ids = adj[wid * CAP + lane];

    float sum = 0.0f;
    int j = 0;
    for (; j + 8 <= cc; j += 8) {
        int i0 = __shfl(ids, j + 0);
        int i1 = __shfl(ids, j + 1);
        int i2 = __shfl(ids, j + 2);
        int i3 = __shfl(ids, j + 3);
        int i4 = __shfl(ids, j + 4);
        int i5 = __shfl(ids, j + 5);
        int i6 = __shfl(ids, j + 6);
        int i7 = __shfl(ids, j + 7);
        float f0 = bf2f(fb[i0 * D_IN + lane]);
        float f1 = bf2f(fb[i1 * D_IN + lane]);
        float f2 = bf2f(fb[i2 * D_IN + lane]);
        float f3 = bf2f(fb[i3 * D_IN + lane]);
        float f4 = bf2f(fb[i4 * D_IN + lane]);
        float f5 = bf2f(fb[i5 * D_IN + lane]);
        float f6 = bf2f(fb[i6 * D_IN + lane]);
        float f7 = bf2f(fb[i7 * D_IN + lane]);
        sum += ((f0 + f1) + (f2 + f3)) + ((f4 + f5) + (f6 + f7));
    }
    for (; j < cc; ++j)
        sum += bf2f(fb[__shfl(ids, j) * D_IN + lane]);

    float m = sum / fmaxf((float)c, 1.0f);
    fm[(size_t)wid * D_IN + lane] = f2bf(m);
}

// fallback aggregates (round 8): bf16 mean IN PLACE over adj row
__global__ __launch_bounds__(256) void aggregate_bf16_kernel(
    const ushortt* __restrict__ fb,
    int* __restrict__ adjmean,
    const int* __restrict__ cnt,
    int N)
{
    int wid  = (blockIdx.x * blockDim.x + threadIdx.x) >> 6;
    int lane = threadIdx.x & 63;
    if (wid >= N) return;

    int c  = cnt[wid];
    int cc = c < CAP_L ? c : CAP_L;
    int ids = adjmean[wid * CAP + lane];

    float sum = 0.0f;
    int j = 0;
    for (; j + 8 <= cc; j += 8) {
        int i0 = __shfl(ids, j + 0);
        int i1 = __shfl(ids, j + 1);
        int i2 = __shfl(ids, j + 2);
        int i3 = __shfl(ids, j + 3);
        int i4 = __shfl(ids, j + 4);
        int i5 = __shfl(ids, j + 5);
        int i6 = __shfl(ids, j + 6);
        int i7 = __shfl(ids, j + 7);
        float f0 = bf2f(fb[i0 * D_IN + lane]);
        float f1 = bf2f(fb[i1 * D_IN + lane]);
        float f2 = bf2f(fb[i2 * D_IN + lane]);
        float f3 = bf2f(fb[i3 * D_IN + lane]);
        float f4 = bf2f(fb[i4 * D_IN + lane]);
        float f5 = bf2f(fb[i5 * D_IN + lane]);
        float f6 = bf2f(fb[i6 * D_IN + lane]);
        float f7 = bf2f(fb[i7 * D_IN + lane]);
        sum += ((f0 + f1) + (f2 + f3)) + ((f4 + f5) + (f6 + f7));
    }
    for (; j < cc; ++j)
        sum += bf2f(fb[__shfl(ids, j) * D_IN + lane]);

    float m = sum / fmaxf((float)c, 1.0f);
    ushortt* mrow = (ushortt*)&adjmean[wid * CAP];
    mrow[lane] = f2bf(m);
}

__global__ __launch_bounds__(256) void aggregate_f32_kernel(
    const float* __restrict__ feat,
    int* __restrict__ adjmean,
    const int* __restrict__ cnt,
    int N)
{
    int wid  = (blockIdx.x * blockDim.x + threadIdx.x) >> 6;
    int lane = threadIdx.x & 63;
    if (wid >= N) return;

    int c  = cnt[wid];
    int cc = c < CAP_L ? c : CAP_L;
    int ids = adjmean[wid * CAP + lane];

    float sum = 0.0f;
    int j = 0;
    for (; j + 8 <= cc; j += 8) {
        int i0 = __shfl(ids, j + 0);
        int i1 = __shfl(ids, j + 1);
        int i2 = __shfl(ids, j + 2);
        int i3 = __shfl(ids, j + 3);
        int i4 = __shfl(ids, j + 4);
        int i5 = __shfl(ids, j + 5);
        int i6 = __shfl(ids, j + 6);
        int i7 = __shfl(ids, j + 7);
        float f0 = feat[i0 * D_IN + lane];
        float f1 = feat[i1 * D_IN + lane];
        float f2 = feat[i2 * D_IN + lane];
        float f3 = feat[i3 * D_IN + lane];
        float f4 = feat[i4 * D_IN + lane];
        float f5 = feat[i5 * D_IN + lane];
        float f6 = feat[i6 * D_IN + lane];
        float f7 = feat[i7 * D_IN + lane];
        sum += ((f0 + f1) + (f2 + f3)) + ((f4 + f5) + (f6 + f7));
    }
    for (; j < cc; ++j)
        sum += feat[__shfl(ids, j) * D_IN + lane];

    float m = sum / fmaxf((float)c, 1.0f);
    ushortt* mrow = (ushortt*)&adjmean[wid * CAP];
    mrow[lane] = f2bf(m);
}

// ---- MFMA gemm: out = relu([fb||fm](bf16) @ Wb^T + b), fp32 accum ----
// Block = 4 waves = 64 nodes x 128 cols. Wave strip = 16 nodes.
// A-frag: m=lane&15 (node), k=quad*8+j (16B global load, frag reused x8).
// B-frag: n=lane&15 (col),  k=quad*8+j from LDS W (stride 136 shorts).
// C/D:    col=lane&15, row=quad*4+reg.
__global__ __launch_bounds__(256) void gemm_mfma_kernel(
    const int* __restrict__ nodes,
    const ushortt* __restrict__ fb,
    const ushortt* __restrict__ fm,
    const ushortt* __restrict__ Wb,
    const float* __restrict__ bias,
    float* __restrict__ out,
    int N)
{
    __shared__ ushortt w_lds[128 * 136];
    __shared__ int gnode[64];

    const int t  = threadIdx.x;
    const int n0 = blockIdx.x * 64;

    if (t < 64) {
        int idx = n0 + t;
        gnode[t] = nodes[idx < N ? idx : N - 1];
    }
    for (int i = t; i < 128 * 16; i += 256) {
        int row = i >> 4, seg = i & 15;
        *(bf16x8*)&w_lds[row * 136 + seg * 8] =
            *(const bf16x8*)&Wb[row * 128 + seg * 8];
    }
    __syncthreads();

    const int w    = t >> 6;
    const int lane = t & 63;
    const int l15  = lane & 15;     // A row (node) AND B col (h)
    const int quad = lane >> 4;

    const int g = gnode[w * 16 + l15];
    const bf16x8 a0 = *(const bf16x8*)&fb[(size_t)g * D_IN +  0 + quad * 8];
    const bf16x8 a1 = *(const bf16x8*)&fb[(size_t)g * D_IN + 32 + quad * 8];
    const bf16x8 a2 = *(const bf16x8*)&fm[(size_t)g * D_IN +  0 + quad * 8];
    const bf16x8 a3 = *(const bf16x8*)&fm[(size_t)g * D_IN + 32 + quad * 8];

#pragma unroll
    for (int tile = 0; tile < 8; ++tile) {
        const int h0 = tile * 16;
        const ushortt* wrow = &w_lds[(h0 + l15) * 136];
        bf16x8 b0 = *(const bf16x8*)&wrow[ 0 + quad * 8];
        bf16x8 b1 = *(const bf16x8*)&wrow[32 + quad * 8];
        bf16x8 b2 = *(const bf16x8*)&wrow[64 + quad * 8];
        bf16x8 b3 = *(const bf16x8*)&wrow[96 + quad * 8];

        f32x4 acc = {0.f, 0.f, 0.f, 0.f};
        acc = __builtin_amdgcn_mfma_f32_16x16x32_bf16(a0, b0, acc, 0, 0, 0);
        acc = __builtin_amdgcn_mfma_f32_16x16x32_bf16(a1, b1, acc, 0, 0, 0);
        acc = __builtin_amdgcn_mfma_f32_16x16x32_bf16(a2, b2, acc, 0, 0, 0);
        acc = __builtin_amdgcn_mfma_f32_16x16x32_bf16(a3, b3, acc, 0, 0, 0);

        const float bh = bias[h0 + l15];
#pragma unroll
        for (int r = 0; r < 4; ++r) {
            int idx = n0 + w * 16 + quad * 4 + r;
            if (idx < N)
                out[(size_t)idx * H_OUT + h0 + l15] = fmaxf(acc[r] + bh, 0.0f);
        }
    }
}

// fallback gemm (round 8): scalar fp32, self fp32 + mean bf16 in-place
__global__ __launch_bounds__(256) void gemm_kernel(
    const int* __restrict__ nodes,
    const float* __restrict__ feat,
    const ushortt* __restrict__ meanb,   // row g at meanb + g*128, 64 used
    const float* __restrict__ W,
    const float* __restrict__ bias,
    float* __restrict__ out,
    int N)
{
    __shared__ float w_lds[64 * 132];
    __shared__ float comb_self[NPB * 68];
    __shared__ float comb_mean[NPB * 68];
    __shared__ int   gnode[NPB];

    const int t  = threadIdx.x;
    const int n0 = blockIdx.x * NPB;

    if (t < NPB) {
        int idx = n0 + t;
        if (idx >= N) idx = N - 1;
        gnode[t] = nodes[idx];
    }
    __syncthreads();

    for (int i = t; i < NPB * 64; i += 256) {
        int n = i >> 6, d = i & 63;
        int g = gnode[n];
        comb_self[n * 68 + d] = feat[g * D_IN + d];
        comb_mean[n * 68 + d] = bf2f(meanb[(size_t)g * 128 + d]);
    }
    for (int i = t; i < H_OUT * 64; i += 256) {
        int h = i >> 6, kk = i & 63;
        w_lds[kk * 132 + h] = W[h * (2 * D_IN) + kk];
    }
    __syncthreads();

    const int tx = t & 31;
    const int ty = t >> 5;
    const int h0 = tx * 4;
    const int nl = ty * 4;

    float acc[4][4];
#pragma unroll
    for (int j = 0; j < 4; j++)
#pragma unroll
        for (int i = 0; i < 4; i++) acc[j][i] = 0.0f;

    for (int kk = 0; kk < 64; kk += 4) {
        float4 wvv[4], cv[4];
#pragma unroll
        for (int i = 0; i < 4; i++)
            wvv[i] = *(const float4*)&w_lds[(kk + i) * 132 + h0];
#pragma unroll
        for (int j = 0; j < 4; j++)
            cv[j] = *(const float4*)&comb_self[(nl + j) * 68 + kk];
#pragma unroll
        for (int j = 0; j < 4; j++) {
            const float* c = (const float*)&cv[j];
#pragma unroll
            for (int i = 0; i < 4; i++) {
                const float* wp = (const float*)&wvv[i];
                acc[j][0] += wp[0] * c[i];
                acc[j][1] += wp[1] * c[i];
                acc[j][2] += wp[2] * c[i];
                acc[j][3] += wp[3] * c[i];
            }
        }
    }
    __syncthreads();

    for (int i = t; i < H_OUT * 64; i += 256) {
        int h = i >> 6, kk = i & 63;
        w_lds[kk * 132 + h] = W[h * (2 * D_IN) + 64 + kk];
    }
    __syncthreads();

    for (int kk = 0; kk < 64; kk += 4) {
        float4 wvv[4], cv[4];
#pragma unroll
        for (int i = 0; i < 4; i++)
            wvv[i] = *(const float4*)&w_lds[(kk + i) * 132 + h0];
#pragma unroll
        for (int j = 0; j < 4; j++)
            cv[j] = *(const float4*)&comb_mean[(nl + j) * 68 + kk];
#pragma unroll
        for (int j = 0; j < 4; j++) {
            const float* c = (const float*)&cv[j];
#pragma unroll
            for (int i = 0; i < 4; i++) {
                const float* wp = (const float*)&wvv[i];
                acc[j][0] += wp[0] * c[i];
                acc[j][1] += wp[1] * c[i];
                acc[j][2] += wp[2] * c[i];
                acc[j][3] += wp[3] * c[i];
            }
        }
    }

    float4 bv = *(const float4*)&bias[h0];
#pragma unroll
    for (int j = 0; j < 4; j++) {
        int n = n0 + nl + j;
        if (n >= N) continue;
        float4 o;
        o.x = fmaxf(acc[j][0] + bv.x, 0.0f);
        o.y = fmaxf(acc[j][1] + bv.y, 0.0f);
        o.z = fmaxf(acc[j][2] + bv.z, 0.0f);
        o.w = fmaxf(acc[j][3] + bv.w, 0.0f);
        *(float4*)&out[(size_t)n * H_OUT + h0] = o;
    }
}

extern "C" void kernel_launch(void* const* d_in, const int* in_sizes, int n_in,
                              void* d_out, int out_size, void* d_ws, size_t ws_size,
                              hipStream_t stream) {
    const int*   nodes = (const int*)d_in[0];
    const float* feat  = (const float*)d_in[1];
    const int*   ei    = (const int*)d_in[2];
    const float* W     = (const float*)d_in[3];
    const float* bias  = (const float*)d_in[4];
    float*       out   = (float*)d_out;

    const int N  = in_sizes[0];
    const int E  = in_sizes[2] / 2;
    const int E2 = 2 * E;

    const int nbuk  = (N + BUK_N - 1) >> BSHIFT;
    const int chunk = (E2 + PASSA_BLOCKS - 1) / PASSA_BLOCKS;
    double ex = (double)chunk * (double)BUK_N / (double)N;
    int scap = ((int)(ex + 5.0 * __builtin_sqrt(ex)) + 31) & ~15;

    // ---- ws layout (64B-aligned sections) ----
    char* base = (char*)d_ws;
    size_t off = 0;
    auto aln = [](size_t x) { return (x + 63) & ~(size_t)63; };
    int* cnt      = (int*)(base + off); off = aln(off + (size_t)N * 4);
    int* ovfn     = (int*)(base + off); off = aln(off + 64);
    int* adjmean  = (int*)(base + off); off = aln(off + (size_t)N * CAP * 4);
    int* blkcnt   = (int*)(base + off); off = aln(off + (size_t)PASSA_BLOCKS * NBUK_MAX * 4);
    ull* ovf      = (ull*)(base + off); off = aln(off + (size_t)OVF_CAP * 8);
    ushortt* Wb   = (ushortt*)(base + off); off = aln(off + (size_t)H_OUT * 2 * D_IN * 2);
    char* big     = base + off;
    unsigned* gbuf = (unsigned*)big;
    ushortt*  fb   = (ushortt*)big;                        // aliases gbuf
    ushortt*  fm   = fb + (size_t)N * D_IN;

    const size_t gbuf_b = (size_t)PASSA_BLOCKS * nbuk * scap * 4;
    const size_t fb_b   = (size_t)N * D_IN * 2;
    const size_t big_mfma = (gbuf_b > 2 * fb_b ? gbuf_b : 2 * fb_b);
    const size_t big_old  = (gbuf_b > fb_b ? gbuf_b : fb_b);

    const bool use_new  = (N <= 131072) && (nbuk <= NBUK_MAX)
                        && (ws_size >= off + big_old);
    const bool use_bf16 = (ws_size >= off + big_old);      // fb fits
    const bool use_mfma = use_new && (ws_size >= off + big_mfma);

    // ---- build adjacency ----
    if (use_new) {
        hipMemsetAsync(ovfn, 0, 16 * sizeof(int), stream);  // cnt set by pass B
        bucket_a_kernel<<<PASSA_BLOCKS, PASSA_THREADS, 0, stream>>>(
            ei, gbuf, blkcnt, ovf, ovfn, E, nbuk, scap, chunk);
        adj_lds_kernel<<<nbuk, 512, 0, stream>>>(gbuf, blkcnt, ovf, ovfn,
                                                 cnt, adjmean, N, nbuk, scap);
    } else {
        hipMemsetAsync(cnt, 0, (size_t)N * sizeof(int), stream);
        hipMemsetAsync(ovfn, 0, 16 * sizeof(int), stream);
        build_adj_kernel<<<2048, 256, 0, stream>>>(ei, cnt, adjmean, E);
    }

    const int ablocks = (int)(((size_t)N * 64 + 255) / 256);
    const int n4f = N * D_IN / 4;

    if (use_mfma) {
        // ---- MFMA path ----
        w_to_bf16_kernel<<<(H_OUT * 2 * D_IN / 4 + 255) / 256, 256, 0, stream>>>(
            (const float4*)W, (ushort4*)Wb, H_OUT * 2 * D_IN / 4);
        feat_to_bf16_kernel<<<(n4f + 255) / 256, 256, 0, stream>>>(
            (const float4*)feat, (ushort4*)fb, n4f);
        aggregate_compact_kernel<<<ablocks, 256, 0, stream>>>(fb, adjmean, cnt,
                                                              fm, N);
        gemm_mfma_kernel<<<(N + 63) / 64, 256, 0, stream>>>(nodes, fb, fm, Wb,
                                                            bias, out, N);
    } else {
        // ---- round-8 fallback path ----
        if (use_bf16) {
            feat_to_bf16_kernel<<<(n4f + 255) / 256, 256, 0, stream>>>(
                (const float4*)feat, (ushort4*)fb, n4f);
            aggregate_bf16_kernel<<<ablocks, 256, 0, stream>>>(fb, adjmean,
                                                               cnt, N);
        } else {
            aggregate_f32_kernel<<<ablocks, 256, 0, stream>>>(feat, adjmean,
                                                              cnt, N);
        }
        gemm_kernel<<<(N + NPB - 1) / NPB, 256, 0, stream>>>(
            nodes, feat, (const ushortt*)adjmean, W, bias, out, N);
    }
}

// Round 10
// 195.924 us; speedup vs baseline: 3.7430x; 1.1099x over previous
//
#include <hip/hip_runtime.h>
#include <hip/hip_bf16.h>

// ---------------------------------------------------------------------------
// Encoder: out = relu([features, mean_neigh(features)] @ W^T + b)
// N=100000, E=1e6 (undirected), D=64, H=128.
//
// Round 10: aggregate was L2-miss bound (FETCH 195MB: 2M random 128B bf16
// rows vs 4MB per-XCD L2). Fix: gather fp8 e4m3 rows (64B = ONE line, fq
// 6.4MB caches ~2x better); 8 lanes x 8B per row -> one wave-load gathers
// 8 neighbors; fp32 accumulate, shfl_xor oct-reduction; bf16 mean written
// in place over the adj row (first 128B), gemm reads it at stride 128.
// fp8 encode+decode both use HW cvt builtins -> self-consistent roundtrip.
// Adj-row load predicated (lane < cc) to skip unused lines.
// Build pipeline unchanged from round 8/9.
//
// ws: cnt | ovfn | adjmean(mean in place) | blkcnt | ovf | Wb |
//     big{gbuf -> fb(bf16) + fq(fp8)}   (gbuf consumed by pass B before
//     fb/fq are written -> aliasing safe; big = max(25.6, 19.2) MB)
// ---------------------------------------------------------------------------

#define D_IN 64
#define H_OUT 128
#define CAP 64            // adjacency row stride (ints)
#define CAP_L 61          // LDS slots per node; max true degree ~45
#define NPB 32            // nodes per block in fallback gemm
#define BSHIFT 8          // 256 nodes per bucket
#define BUK_N 256
#define NBUK_MAX 512
#define PASSA_BLOCKS 256
#define PASSA_THREADS 512
#define OVF_CAP 32768

typedef unsigned long long ull;
typedef unsigned short ushortt;
typedef unsigned char uchar;
typedef __attribute__((ext_vector_type(8))) short bf16x8;
typedef __attribute__((ext_vector_type(4))) float f32x4;
typedef __attribute__((ext_vector_type(2))) float f32x2;

__device__ __forceinline__ ushortt f2bf(float f) {
    __hip_bfloat16 h = __float2bfloat16(f);
    return *reinterpret_cast<ushortt*>(&h);
}
__device__ __forceinline__ float bf2f(ushortt u) {
    unsigned int x = ((unsigned int)u) << 16;
    return __uint_as_float(x);
}

// ---- pass A: per-block private bucketing, no global atomics ----
__global__ __launch_bounds__(PASSA_THREADS) void bucket_a_kernel(
    const int* __restrict__ ei,
    unsigned* __restrict__ gbuf,
    int* __restrict__ blkcnt,
    ull* __restrict__ ovf,
    int* __restrict__ ovfn,
    int E, int nbuk, int scap, int chunk)
{
    __shared__ int lcnt[NBUK_MAX];
    const int t = threadIdx.x;
    for (int i = t; i < nbuk; i += PASSA_THREADS) lcnt[i] = 0;
    __syncthreads();

    const int E2 = 2 * E;
    int lo = blockIdx.x * chunk;
    int hi = lo + chunk; if (hi > E2) hi = E2;

    for (int i = lo + t; i < hi; i += PASSA_THREADS) {
        int u = ei[i];
        int v = (i < E) ? ei[E + i] : ei[i - E];
        int b = u >> BSHIFT;
        unsigned pk = ((unsigned)v << BSHIFT) | (unsigned)(u & (BUK_N - 1));
        int p = atomicAdd(&lcnt[b], 1);          // LDS atomic: cheap
        if (p < scap) {
            gbuf[((size_t)blockIdx.x * nbuk + b) * scap + p] = pk;
        } else {                                  // statistically ~never
            int gp = atomicAdd(ovfn, 1);
            if (gp < OVF_CAP) ovf[gp] = ((ull)(unsigned)v << 32) | (unsigned)u;
        }
    }
    __syncthreads();
    for (int b = t; b < nbuk; b += PASSA_THREADS) {
        int c = lcnt[b];
        blkcnt[blockIdx.x * nbuk + b] = c < scap ? c : scap;
    }
}

// ---- pass B: one block per bucket; adjacency assembled in LDS ----
__global__ __launch_bounds__(512) void adj_lds_kernel(
    const unsigned* __restrict__ gbuf,
    const int* __restrict__ blkcnt,
    const ull* __restrict__ ovf,
    const int* __restrict__ ovfn,
    int* __restrict__ cnt,
    int* __restrict__ adj,
    int N, int nbuk, int scap)
{
    __shared__ unsigned adj_l[BUK_N * CAP_L];   // stride 61: bank-perm on node
    __shared__ int cnt_l[BUK_N];
    __shared__ int scnt_l[PASSA_BLOCKS];

    const int b = blockIdx.x;
    const int t = threadIdx.x;

    if (t < BUK_N) cnt_l[t] = 0;
    if (t < PASSA_BLOCKS) scnt_l[t] = blkcnt[t * nbuk + b];
    __syncthreads();

    const int wv   = t >> 6;
    const int lane = t & 63;

    for (int seg = wv; seg < PASSA_BLOCKS; seg += 8) {
        int c = scnt_l[seg];
        const unsigned* base = gbuf + ((size_t)seg * nbuk + b) * scap;
        for (int i = lane; i < c; i += 64) {
            unsigned e = base[i];
            int ul = e & (BUK_N - 1);
            int v  = (int)(e >> BSHIFT);
            int p  = atomicAdd(&cnt_l[ul], 1);
            if (p < CAP_L) adj_l[ul * CAP_L + p] = (unsigned)v;
        }
    }
    __syncthreads();

    int novf = *ovfn; if (novf > OVF_CAP) novf = OVF_CAP;
    for (int i = t; i < novf; i += 512) {
        ull pk = ovf[i];
        int u = (int)(unsigned)(pk & 0xffffffffu);
        if ((u >> BSHIFT) == b) {
            int v = (int)(unsigned)(pk >> 32);
            int ul = u & (BUK_N - 1);
            int p  = atomicAdd(&cnt_l[ul], 1);
            if (p < CAP_L) adj_l[ul * CAP_L + p] = (unsigned)v;
        }
    }
    __syncthreads();

    if (t < BUK_N) {
        int g = (b << BSHIFT) + t;
        if (g < N) {
            int c = cnt_l[t];
            cnt[g] = c;
            int cl = c < CAP_L ? c : CAP_L;
            int k4 = (cl + 3) >> 2;
            for (int s = 0; s < k4; ++s) {
                uint4 o;
                o.x = adj_l[t * CAP_L + 4 * s + 0];
                o.y = adj_l[t * CAP_L + 4 * s + 1];
                o.z = adj_l[t * CAP_L + 4 * s + 2];
                o.w = adj_l[t * CAP_L + 4 * s + 3];
                *(uint4*)&adj[(size_t)g * CAP + 4 * s] = o;
            }
        }
    }
}

// ---- fallback build (round 5): XCD-partitioned single pass ----
__global__ __launch_bounds__(256) void build_adj_kernel(
    const int* __restrict__ ei,
    int* __restrict__ cnt,
    int* __restrict__ adj,
    int E)
{
    const int part   = blockIdx.x & 7;
    const int bloc   = blockIdx.x >> 3;
    const int nbp    = gridDim.x >> 3;
    const int stride = nbp * 256;
    const int E2     = 2 * E;

    for (int i = bloc * 256 + (int)threadIdx.x; i < E2; i += stride) {
        int u = ei[i];
        if (((u >> 4) & 7) != part) continue;
        int v = (i < E) ? ei[E + i] : ei[i - E];
        int p = atomicAdd(&cnt[u], 1);
        if (p < CAP_L) adj[u * CAP + p] = v;
    }
}

// ---- fused conversion: feat -> fb(bf16) + fq(fp8 e4m3); W -> Wb(bf16) ----
__global__ __launch_bounds__(256) void convert_kernel(
    const float4* __restrict__ feat4,
    const float4* __restrict__ w4,
    ushortt* __restrict__ fb,
    uint2* __restrict__ fq,        // 8 fp8 per element
    ushortt* __restrict__ Wb,
    int nfeat8, int nw8)
{
    int i = blockIdx.x * 256 + threadIdx.x;
    if (i < nfeat8) {
        float4 a = feat4[2 * i], b = feat4[2 * i + 1];
        bf16x8 o;
        o[0] = (short)f2bf(a.x); o[1] = (short)f2bf(a.y);
        o[2] = (short)f2bf(a.z); o[3] = (short)f2bf(a.w);
        o[4] = (short)f2bf(b.x); o[5] = (short)f2bf(b.y);
        o[6] = (short)f2bf(b.z); o[7] = (short)f2bf(b.w);
        *(bf16x8*)&fb[(size_t)i * 8] = o;
        unsigned lo = (unsigned)__builtin_amdgcn_cvt_pk_fp8_f32(a.x, a.y, 0, false);
        lo = (unsigned)__builtin_amdgcn_cvt_pk_fp8_f32(a.z, a.w, (int)lo, true);
        unsigned hi = (unsigned)__builtin_amdgcn_cvt_pk_fp8_f32(b.x, b.y, 0, false);
        hi = (unsigned)__builtin_amdgcn_cvt_pk_fp8_f32(b.z, b.w, (int)hi, true);
        uint2 q; q.x = lo; q.y = hi;
        fq[i] = q;
    } else {
        int j = i - nfeat8;
        if (j < nw8) {
            float4 a = w4[2 * j], b = w4[2 * j + 1];
            bf16x8 o;
            o[0] = (short)f2bf(a.x); o[1] = (short)f2bf(a.y);
            o[2] = (short)f2bf(a.z); o[3] = (short)f2bf(a.w);
            o[4] = (short)f2bf(b.x); o[5] = (short)f2bf(b.y);
            o[6] = (short)f2bf(b.z); o[7] = (short)f2bf(b.w);
            *(bf16x8*)&Wb[(size_t)j * 8] = o;
        }
    }
}

// ---- fp8 gather aggregate: one wave per node, 8 neighbor rows per load ----
// oct = lane>>3 handles neighbor j+oct; ol = lane&7 covers dims 8ol..8ol+7
// (uint2 = 8 fp8 = 64B row per 8 lanes = ONE cache line per neighbor row).
// fp32 accumulate; oct-reduction via shfl_xor(8,16,32); bf16 mean written
// in place over the adj row's first 128B.
__global__ __launch_bounds__(256) void aggregate_fp8_kernel(
    const uchar* __restrict__ fq,
    int* __restrict__ adjmean,
    const int* __restrict__ cnt,
    int N)
{
    int wid  = (blockIdx.x * blockDim.x + threadIdx.x) >> 6;
    int lane = threadIdx.x & 63;
    if (wid >= N) return;

    const int oct = lane >> 3;
    const int ol  = lane & 7;

    int c  = cnt[wid];
    int cc = c < CAP_L ? c : CAP_L;

    int ids = 0;
    if (lane < cc) ids = adjmean[wid * CAP + lane];   // predicated: ~2 lines

    float s[8];
#pragma unroll
    for (int k = 0; k < 8; ++k) s[k] = 0.0f;

    for (int j = 0; j < cc; j += 16) {
        int j0 = j + oct;
        int j1 = j + 8 + oct;
        int a0 = j0 < cc;
        int a1 = j1 < cc;
        int id0 = __shfl(ids, a0 ? j0 : cc - 1);
        int id1 = __shfl(ids, a1 ? j1 : cc - 1);
        uint2 u0 = *(const uint2*)(fq + (size_t)id0 * 64 + ol * 8);
        uint2 u1 = *(const uint2*)(fq + (size_t)id1 * 64 + ol * 8);
        if (!a0) { u0.x = 0u; u0.y = 0u; }   // fp8 0x00 == 0.0
        if (!a1) { u1.x = 0u; u1.y = 0u; }
        f32x2 p;
        p = __builtin_amdgcn_cvt_pk_f32_fp8((int)u0.x, false); s[0] += p.x; s[1] += p.y;
        p = __builtin_amdgcn_cvt_pk_f32_fp8((int)u0.x, true);  s[2] += p.x; s[3] += p.y;
        p = __builtin_amdgcn_cvt_pk_f32_fp8((int)u0.y, false); s[4] += p.x; s[5] += p.y;
        p = __builtin_amdgcn_cvt_pk_f32_fp8((int)u0.y, true);  s[6] += p.x; s[7] += p.y;
        p = __builtin_amdgcn_cvt_pk_f32_fp8((int)u1.x, false); s[0] += p.x; s[1] += p.y;
        p = __builtin_amdgcn_cvt_pk_f32_fp8((int)u1.x, true);  s[2] += p.x; s[3] += p.y;
        p = __builtin_amdgcn_cvt_pk_f32_fp8((int)u1.y, false); s[4] += p.x; s[5] += p.y;
        p = __builtin_amdgcn_cvt_pk_f32_fp8((int)u1.y, true);  s[6] += p.x; s[7] += p.y;
    }

    // reduce across octs (lane bits 3,4,5)
#pragma unroll
    for (int m = 8; m <= 32; m <<= 1) {
#pragma unroll
        for (int k = 0; k < 8; ++k) s[k] += __shfl_xor(s[k], m);
    }

    if (oct == 0) {
        float r = 1.0f / fmaxf((float)c, 1.0f);
        bf16x8 o;
#pragma unroll
        for (int k = 0; k < 8; ++k) o[k] = (short)f2bf(s[k] * r);
        ushortt* mrow = (ushortt*)&adjmean[wid * CAP];   // first 128B of row
        *(bf16x8*)&mrow[ol * 8] = o;
    }
}

// fallback aggregates: bf16/f32 gather, bf16 mean IN PLACE over adj row
__global__ __launch_bounds__(256) void aggregate_bf16_kernel(
    const ushortt* __restrict__ fb,
    int* __restrict__ adjmean,
    const int* __restrict__ cnt,
    int N)
{
    int wid  = (blockIdx.x * blockDim.x + threadIdx.x) >> 6;
    int lane = threadIdx.x & 63;
    if (wid >= N) return;

    int c  = cnt[wid];
    int cc = c < CAP_L ? c : CAP_L;
    int ids = adjmean[wid * CAP + lane];

    float sum = 0.0f;
    int j = 0;
    for (; j + 8 <= cc; j += 8) {
        int i0 = __shfl(ids, j + 0);
        int i1 = __shfl(ids, j + 1);
        int i2 = __shfl(ids, j + 2);
        int i3 = __shfl(ids, j + 3);
        int i4 = __shfl(ids, j + 4);
        int i5 = __shfl(ids, j + 5);
        int i6 = __shfl(ids, j + 6);
        int i7 = __shfl(ids, j + 7);
        float f0 = bf2f(fb[i0 * D_IN + lane]);
        float f1 = bf2f(fb[i1 * D_IN + lane]);
        float f2 = bf2f(fb[i2 * D_IN + lane]);
        float f3 = bf2f(fb[i3 * D_IN + lane]);
        float f4 = bf2f(fb[i4 * D_IN + lane]);
        float f5 = bf2f(fb[i5 * D_IN + lane]);
        float f6 = bf2f(fb[i6 * D_IN + lane]);
        float f7 = bf2f(fb[i7 * D_IN + lane]);
        sum += ((f0 + f1) + (f2 + f3)) + ((f4 + f5) + (f6 + f7));
    }
    for (; j < cc; ++j)
        sum += bf2f(fb[__shfl(ids, j) * D_IN + lane]);

    float m = sum / fmaxf((float)c, 1.0f);
    ushortt* mrow = (ushortt*)&adjmean[wid * CAP];
    mrow[lane] = f2bf(m);
}

__global__ __launch_bounds__(256) void aggregate_f32_kernel(
    const float* __restrict__ feat,
    int* __restrict__ adjmean,
    const int* __restrict__ cnt,
    int N)
{
    int wid  = (blockIdx.x * blockDim.x + threadIdx.x) >> 6;
    int lane = threadIdx.x & 63;
    if (wid >= N) return;

    int c  = cnt[wid];
    int cc = c < CAP_L ? c : CAP_L;
    int ids = adjmean[wid * CAP + lane];

    float sum = 0.0f;
    int j = 0;
    for (; j + 8 <= cc; j += 8) {
        int i0 = __shfl(ids, j + 0);
        int i1 = __shfl(ids, j + 1);
        int i2 = __shfl(ids, j + 2);
        int i3 = __shfl(ids, j + 3);
        int i4 = __shfl(ids, j + 4);
        int i5 = __shfl(ids, j + 5);
        int i6 = __shfl(ids, j + 6);
        int i7 = __shfl(ids, j + 7);
        float f0 = feat[i0 * D_IN + lane];
        float f1 = feat[i1 * D_IN + lane];
        float f2 = feat[i2 * D_IN + lane];
        float f3 = feat[i3 * D_IN + lane];
        float f4 = feat[i4 * D_IN + lane];
        float f5 = feat[i5 * D_IN + lane];
        float f6 = feat[i6 * D_IN + lane];
        float f7 = feat[i7 * D_IN + lane];
        sum += ((f0 + f1) + (f2 + f3)) + ((f4 + f5) + (f6 + f7));
    }
    for (; j < cc; ++j)
        sum += feat[__shfl(ids, j) * D_IN + lane];

    float m = sum / fmaxf((float)c, 1.0f);
    ushortt* mrow = (ushortt*)&adjmean[wid * CAP];
    mrow[lane] = f2bf(m);
}

// ---- MFMA gemm: out = relu([fb||mean](bf16) @ Wb^T + b), fp32 accum ----
// mean row g = first 64 shorts of adj row g (stride 128 shorts).
__global__ __launch_bounds__(256) void gemm_mfma_kernel(
    const int* __restrict__ nodes,
    const ushortt* __restrict__ fb,
    const ushortt* __restrict__ meanb,   // row g at meanb + g*128
    const ushortt* __restrict__ Wb,
    const float* __restrict__ bias,
    float* __restrict__ out,
    int N)
{
    __shared__ ushortt w_lds[128 * 136];
    __shared__ int gnode[64];

    const int t  = threadIdx.x;
    const int n0 = blockIdx.x * 64;

    if (t < 64) {
        int idx = n0 + t;
        gnode[t] = nodes[idx < N ? idx : N - 1];
    }
    for (int i = t; i < 128 * 16; i += 256) {
        int row = i >> 4, seg = i & 15;
        *(bf16x8*)&w_lds[row * 136 + seg * 8] =
            *(const bf16x8*)&Wb[row * 128 + seg * 8];
    }
    __syncthreads();

    const int w    = t >> 6;
    const int lane = t & 63;
    const int l15  = lane & 15;     // A row (node) AND B col (h)
    const int quad = lane >> 4;

    const int g = gnode[w * 16 + l15];
    const bf16x8 a0 = *(const bf16x8*)&fb[(size_t)g * D_IN +  0 + quad * 8];
    const bf16x8 a1 = *(const bf16x8*)&fb[(size_t)g * D_IN + 32 + quad * 8];
    const bf16x8 a2 = *(const bf16x8*)&meanb[(size_t)g * 128 +  0 + quad * 8];
    const bf16x8 a3 = *(const bf16x8*)&meanb[(size_t)g * 128 + 32 + quad * 8];

#pragma unroll
    for (int tile = 0; tile < 8; ++tile) {
        const int h0 = tile * 16;
        const ushortt* wrow = &w_lds[(h0 + l15) * 136];
        bf16x8 b0 = *(const bf16x8*)&wrow[ 0 + quad * 8];
        bf16x8 b1 = *(const bf16x8*)&wrow[32 + quad * 8];
        bf16x8 b2 = *(const bf16x8*)&wrow[64 + quad * 8];
        bf16x8 b3 = *(const bf16x8*)&wrow[96 + quad * 8];

        f32x4 acc = {0.f, 0.f, 0.f, 0.f};
        acc = __builtin_amdgcn_mfma_f32_16x16x32_bf16(a0, b0, acc, 0, 0, 0);
        acc = __builtin_amdgcn_mfma_f32_16x16x32_bf16(a1, b1, acc, 0, 0, 0);
        acc = __builtin_amdgcn_mfma_f32_16x16x32_bf16(a2, b2, acc, 0, 0, 0);
        acc = __builtin_amdgcn_mfma_f32_16x16x32_bf16(a3, b3, acc, 0, 0, 0);

        const float bh = bias[h0 + l15];
#pragma unroll
        for (int r = 0; r < 4; ++r) {
            int idx = n0 + w * 16 + quad * 4 + r;
            if (idx < N)
                out[(size_t)idx * H_OUT + h0 + l15] = fmaxf(acc[r] + bh, 0.0f);
        }
    }
}

// fallback gemm (round 8): scalar fp32, self fp32 + mean bf16 in-place
__global__ __launch_bounds__(256) void gemm_kernel(
    const int* __restrict__ nodes,
    const float* __restrict__ feat,
    const ushortt* __restrict__ meanb,   // row g at meanb + g*128, 64 used
    const float* __restrict__ W,
    const float* __restrict__ bias,
    float* __restrict__ out,
    int N)
{
    __shared__ float w_lds[64 * 132];
    __shared__ float comb_self[NPB * 68];
    __shared__ float comb_mean[NPB * 68];
    __shared__ int   gnode[NPB];

    const int t  = threadIdx.x;
    const int n0 = blockIdx.x * NPB;

    if (t < NPB) {
        int idx = n0 + t;
        if (idx >= N) idx = N - 1;
        gnode[t] = nodes[idx];
    }
    __syncthreads();

    for (int i = t; i < NPB * 64; i += 256) {
        int n = i >> 6, d = i & 63;
        int g = gnode[n];
        comb_self[n * 68 + d] = feat[g * D_IN + d];
        comb_mean[n * 68 + d] = bf2f(meanb[(size_t)g * 128 + d]);
    }
    for (int i = t; i < H_OUT * 64; i += 256) {
        int h = i >> 6, kk = i & 63;
        w_lds[kk * 132 + h] = W[h * (2 * D_IN) + kk];
    }
    __syncthreads();

    const int tx = t & 31;
    const int ty = t >> 5;
    const int h0 = tx * 4;
    const int nl = ty * 4;

    float acc[4][4];
#pragma unroll
    for (int j = 0; j < 4; j++)
#pragma unroll
        for (int i = 0; i < 4; i++) acc[j][i] = 0.0f;

    for (int kk = 0; kk < 64; kk += 4) {
        float4 wvv[4], cv[4];
#pragma unroll
        for (int i = 0; i < 4; i++)
            wvv[i] = *(const float4*)&w_lds[(kk + i) * 132 + h0];
#pragma unroll
        for (int j = 0; j < 4; j++)
            cv[j] = *(const float4*)&comb_self[(nl + j) * 68 + kk];
#pragma unroll
        for (int j = 0; j < 4; j++) {
            const float* c = (const float*)&cv[j];
#pragma unroll
            for (int i = 0; i < 4; i++) {
                const float* wp = (const float*)&wvv[i];
                acc[j][0] += wp[0] * c[i];
                acc[j][1] += wp[1] * c[i];
                acc[j][2] += wp[2] * c[i];
                acc[j][3] += wp[3] * c[i];
            }
        }
    }
    __syncthreads();

    for (int i = t; i < H_OUT * 64; i += 256) {
        int h = i >> 6, kk = i & 63;
        w_lds[kk * 132 + h] = W[h * (2 * D_IN) + 64 + kk];
    }
    __syncthreads();

    for (int kk = 0; kk < 64; kk += 4) {
        float4 wvv[4], cv[4];
#pragma unroll
        for (int i = 0; i < 4; i++)
            wvv[i] = *(const float4*)&w_lds[(kk + i) * 132 + h0];
#pragma unroll
        for (int j = 0; j < 4; j++)
            cv[j] = *(const float4*)&comb_mean[(nl + j) * 68 + kk];
#pragma unroll
        for (int j = 0; j < 4; j++) {
            const float* c = (const float*)&cv[j];
#pragma unroll
            for (int i = 0; i < 4; i++) {
                const float* wp = (const float*)&wvv[i];
                acc[j][0] += wp[0] * c[i];
                acc[j][1] += wp[1] * c[i];
                acc[j][2] += wp[2] * c[i];
                acc[j][3] += wp[3] * c[i];
            }
        }
    }

    float4 bv = *(const float4*)&bias[h0];
#pragma unroll
    for (int j = 0; j < 4; j++) {
        int n = n0 + nl + j;
        if (n >= N) continue;
        float4 o;
        o.x = fmaxf(acc[j][0] + bv.x, 0.0f);
        o.y = fmaxf(acc[j][1] + bv.y, 0.0f);
        o.z = fmaxf(acc[j][2] + bv.z, 0.0f);
        o.w = fmaxf(acc[j][3] + bv.w, 0.0f);
        *(float4*)&out[(size_t)n * H_OUT + h0] = o;
    }
}

extern "C" void kernel_launch(void* const* d_in, const int* in_sizes, int n_in,
                              void* d_out, int out_size, void* d_ws, size_t ws_size,
                              hipStream_t stream) {
    const int*   nodes = (const int*)d_in[0];
    const float* feat  = (const float*)d_in[1];
    const int*   ei    = (const int*)d_in[2];
    const float* W     = (const float*)d_in[3];
    const float* bias  = (const float*)d_in[4];
    float*       out   = (float*)d_out;

    const int N  = in_sizes[0];
    const int E  = in_sizes[2] / 2;
    const int E2 = 2 * E;

    const int nbuk  = (N + BUK_N - 1) >> BSHIFT;
    const int chunk = (E2 + PASSA_BLOCKS - 1) / PASSA_BLOCKS;
    double ex = (double)chunk * (double)BUK_N / (double)N;
    int scap = ((int)(ex + 5.0 * __builtin_sqrt(ex)) + 31) & ~15;

    // ---- ws layout (64B-aligned sections) ----
    char* base = (char*)d_ws;
    size_t off = 0;
    auto aln = [](size_t x) { return (x + 63) & ~(size_t)63; };
    int* cnt      = (int*)(base + off); off = aln(off + (size_t)N * 4);
    int* ovfn     = (int*)(base + off); off = aln(off + 64);
    int* adjmean  = (int*)(base + off); off = aln(off + (size_t)N * CAP * 4);
    int* blkcnt   = (int*)(base + off); off = aln(off + (size_t)PASSA_BLOCKS * NBUK_MAX * 4);
    ull* ovf      = (ull*)(base + off); off = aln(off + (size_t)OVF_CAP * 8);
    ushortt* Wb   = (ushortt*)(base + off); off = aln(off + (size_t)H_OUT * 2 * D_IN * 2);
    char* big     = base + off;
    unsigned* gbuf = (unsigned*)big;
    ushortt*  fb   = (ushortt*)big;                        // aliases gbuf
    uchar*    fq   = (uchar*)(fb + (size_t)N * D_IN);      // fp8, after fb

    const size_t gbuf_b  = (size_t)PASSA_BLOCKS * nbuk * scap * 4;
    const size_t fb_b    = (size_t)N * D_IN * 2;
    const size_t fq_b    = (size_t)N * D_IN;
    const size_t big_mfma = (gbuf_b > fb_b + fq_b ? gbuf_b : fb_b + fq_b);
    const size_t big_old  = (gbuf_b > fb_b ? gbuf_b : fb_b);

    const bool use_new  = (N <= 131072) && (nbuk <= NBUK_MAX)
                        && (ws_size >= off + big_old);
    const bool use_bf16 = (ws_size >= off + big_old);      // fb fits
    const bool use_mfma = use_new && (ws_size >= off + big_mfma);

    // ---- build adjacency ----
    if (use_new) {
        hipMemsetAsync(ovfn, 0, 16 * sizeof(int), stream);  // cnt set by pass B
        bucket_a_kernel<<<PASSA_BLOCKS, PASSA_THREADS, 0, stream>>>(
            ei, gbuf, blkcnt, ovf, ovfn, E, nbuk, scap, chunk);
        adj_lds_kernel<<<nbuk, 512, 0, stream>>>(gbuf, blkcnt, ovf, ovfn,
                                                 cnt, adjmean, N, nbuk, scap);
    } else {
        hipMemsetAsync(cnt, 0, (size_t)N * sizeof(int), stream);
        hipMemsetAsync(ovfn, 0, 16 * sizeof(int), stream);
        build_adj_kernel<<<2048, 256, 0, stream>>>(ei, cnt, adjmean, E);
    }

    const int ablocks = (int)(((size_t)N * 64 + 255) / 256);
    const int n4f = N * D_IN / 4;

    if (use_mfma) {
        // ---- fp8-gather MFMA path ----
        const int nfeat8 = N * D_IN / 8;
        const int nw8    = H_OUT * 2 * D_IN / 8;
        convert_kernel<<<(nfeat8 + nw8 + 255) / 256, 256, 0, stream>>>(
            (const float4*)feat, (const float4*)W, fb, (uint2*)fq, Wb,
            nfeat8, nw8);
        aggregate_fp8_kernel<<<ablocks, 256, 0, stream>>>(fq, adjmean, cnt, N);
        gemm_mfma_kernel<<<(N + 63) / 64, 256, 0, stream>>>(
            nodes, fb, (const ushortt*)adjmean, Wb, bias, out, N);
    } else {
        // ---- round-8 fallback path ----
        if (use_bf16) {
            convert_kernel<<<(N * D_IN / 8 + 255) / 256, 256, 0, stream>>>(
                (const float4*)feat, (const float4*)W, fb, (uint2*)fq, Wb,
                N * D_IN / 8, 0);
            aggregate_bf16_kernel<<<ablocks, 256, 0, stream>>>(fb, adjmean,
                                                               cnt, N);
        } else {
            aggregate_f32_kernel<<<ablocks, 256, 0, stream>>>(feat, adjmean,
                                                              cnt, N);
        }
        gemm_kernel<<<(N + NPB - 1) / NPB, 256, 0, stream>>>(
            nodes, feat, (const ushortt*)adjmean, W, bias, out, N);
    }
}